// Round 1
// baseline (5944.107 us; speedup 1.0000x reference)
//
#include <hip/hip_runtime.h>
#include <hip/hip_bf16.h>

#define N_NODES 100000

// ---------------------------------------------------------------------------
// Hardware float atomic add (global_atomic_add_f32). Plain atomicAdd(float*)
// can compile to a CAS loop without -munsafe-fp-atomics.
__device__ __forceinline__ void atomAddF(float* p, float v) {
    unsafeAtomicAdd(p, v);
}

// ---------------------------------------------------------------------------
// Scatter-add of 128-wide feature rows: agg[dst] += feat[src], deg[dst] += 1.
// 32 threads per edge, each thread handles one float4 (4 features).
__global__ __launch_bounds__(256) void scatter_kernel(
    const float* __restrict__ feat, const int* __restrict__ src,
    const int* __restrict__ dst, float* __restrict__ agg,
    float* __restrict__ deg, long long E)
{
    long long tid = (long long)blockIdx.x * blockDim.x + threadIdx.x;
    long long e = tid >> 5;
    int q = (int)(tid & 31);
    if (e >= E) return;
    int s = src[e];
    int d = dst[e];
    const float4* row = (const float4*)(feat + (size_t)s * 128);
    float4 v = row[q];
    float* ap = agg + (size_t)d * 128 + (size_t)q * 4;
    atomAddF(ap + 0, v.x);
    atomAddF(ap + 1, v.y);
    atomAddF(ap + 2, v.z);
    atomAddF(ap + 3, v.w);
    if (deg != nullptr && q == 0) atomAddF(deg + d, 1.0f);
}

// ---------------------------------------------------------------------------
// Layer 1: h[n,j] = relu( (agg[n,:]/max(deg,1)) . W1l[j,:] + b1[j] + x[n,:] . W1r[j,:] )
// 8 nodes per block, 128 threads (thread j = output feature j).
__global__ __launch_bounds__(128) void layer1_kernel(
    const float* __restrict__ agg, const float* __restrict__ x,
    const float* __restrict__ deg,
    const float* __restrict__ W1l, const float* __restrict__ b1,
    const float* __restrict__ W1r, float* __restrict__ h)
{
    __shared__ float a_s[8][128];
    __shared__ float x_s[8][128];
    int node0 = blockIdx.x * 8;

    for (int i = threadIdx.x; i < 8 * 128; i += 128) {
        int k = i >> 7;
        int f = i & 127;
        int n = node0 + k;
        float av = 0.0f, xv = 0.0f;
        if (n < N_NODES) {
            float inv = 1.0f / fmaxf(deg[n], 1.0f);
            av = agg[(size_t)n * 128 + f] * inv;
            xv = x[(size_t)n * 128 + f];
        }
        a_s[k][f] = av;
        x_s[k][f] = xv;
    }
    __syncthreads();

    int j = threadIdx.x;
    float acc[8];
    float bv = b1[j];
    #pragma unroll
    for (int k = 0; k < 8; k++) acc[k] = bv;

    const float4* Wl4 = (const float4*)(W1l + (size_t)j * 128);
    const float4* Wr4 = (const float4*)(W1r + (size_t)j * 128);
    for (int f4 = 0; f4 < 32; f4++) {
        float4 wl = Wl4[f4];
        float4 wr = Wr4[f4];
        int f = f4 * 4;
        #pragma unroll
        for (int k = 0; k < 8; k++) {
            acc[k] += a_s[k][f + 0] * wl.x + a_s[k][f + 1] * wl.y
                    + a_s[k][f + 2] * wl.z + a_s[k][f + 3] * wl.w
                    + x_s[k][f + 0] * wr.x + x_s[k][f + 1] * wr.y
                    + x_s[k][f + 2] * wr.z + x_s[k][f + 3] * wr.w;
        }
    }

    #pragma unroll
    for (int k = 0; k < 8; k++) {
        int n = node0 + k;
        if (n < N_NODES) h[(size_t)n * 128 + j] = fmaxf(acc[k], 0.0f);
    }
}

// ---------------------------------------------------------------------------
// Layer 2 + log_softmax: out[n,c] = logsoftmax_c( (agg2[n,:]/deg) . W2l[c,:]
//                                  + b2[c] + h[n,:] . W2r[c,:] )
// 8 nodes per block, 64 threads (one wave; thread c = class c).
__global__ __launch_bounds__(64) void layer2_kernel(
    const float* __restrict__ agg, const float* __restrict__ h,
    const float* __restrict__ deg,
    const float* __restrict__ W2l, const float* __restrict__ b2,
    const float* __restrict__ W2r, float* __restrict__ out)
{
    __shared__ float a_s[8][128];
    __shared__ float h_s[8][128];
    int node0 = blockIdx.x * 8;

    for (int i = threadIdx.x; i < 8 * 128; i += 64) {
        int k = i >> 7;
        int f = i & 127;
        int n = node0 + k;
        float av = 0.0f, hv = 0.0f;
        if (n < N_NODES) {
            float inv = 1.0f / fmaxf(deg[n], 1.0f);
            av = agg[(size_t)n * 128 + f] * inv;
            hv = h[(size_t)n * 128 + f];
        }
        a_s[k][f] = av;
        h_s[k][f] = hv;
    }
    __syncthreads();

    int c = threadIdx.x;  // 0..63
    float acc[8];
    float bv = b2[c];
    #pragma unroll
    for (int k = 0; k < 8; k++) acc[k] = bv;

    const float4* Wl4 = (const float4*)(W2l + (size_t)c * 128);
    const float4* Wr4 = (const float4*)(W2r + (size_t)c * 128);
    for (int f4 = 0; f4 < 32; f4++) {
        float4 wl = Wl4[f4];
        float4 wr = Wr4[f4];
        int f = f4 * 4;
        #pragma unroll
        for (int k = 0; k < 8; k++) {
            acc[k] += a_s[k][f + 0] * wl.x + a_s[k][f + 1] * wl.y
                    + a_s[k][f + 2] * wl.z + a_s[k][f + 3] * wl.w
                    + h_s[k][f + 0] * wr.x + h_s[k][f + 1] * wr.y
                    + h_s[k][f + 2] * wr.z + h_s[k][f + 3] * wr.w;
        }
    }

    // log_softmax over the 64 classes (= 64 lanes of this wave), per node.
    #pragma unroll
    for (int k = 0; k < 8; k++) {
        float v = acc[k];
        float m = v;
        #pragma unroll
        for (int off = 1; off < 64; off <<= 1)
            m = fmaxf(m, __shfl_xor(m, off, 64));
        float e = expf(v - m);
        float s = e;
        #pragma unroll
        for (int off = 1; off < 64; off <<= 1)
            s += __shfl_xor(s, off, 64);
        int n = node0 + k;
        if (n < N_NODES) out[(size_t)n * 64 + c] = v - m - logf(s);
    }
}

// ---------------------------------------------------------------------------
extern "C" void kernel_launch(void* const* d_in, const int* in_sizes, int n_in,
                              void* d_out, int out_size, void* d_ws, size_t ws_size,
                              hipStream_t stream)
{
    const float* x   = (const float*)d_in[0];
    const int*   ei  = (const int*)d_in[1];
    const float* W1l = (const float*)d_in[2];
    const float* b1  = (const float*)d_in[3];
    const float* W1r = (const float*)d_in[4];
    const float* W2l = (const float*)d_in[5];
    const float* b2  = (const float*)d_in[6];
    const float* W2r = (const float*)d_in[7];
    float* out = (float*)d_out;

    long long E = (long long)in_sizes[1] / 2;
    const int* src = ei;
    const int* dst = ei + E;

    // workspace layout: agg [N*128] | h [N*128] | deg [N]
    float* agg = (float*)d_ws;
    float* h   = agg + (size_t)N_NODES * 128;
    float* deg = h + (size_t)N_NODES * 128;
    size_t aggBytes = (size_t)N_NODES * 128 * sizeof(float);

    hipMemsetAsync(agg, 0, aggBytes, stream);
    hipMemsetAsync(deg, 0, (size_t)N_NODES * sizeof(float), stream);

    long long scatterThreads = E * 32;
    int scatterBlocks = (int)((scatterThreads + 255) / 256);
    int nodeBlocks = (N_NODES + 7) / 8;

    // Layer 1
    scatter_kernel<<<scatterBlocks, 256, 0, stream>>>(x, src, dst, agg, deg, E);
    layer1_kernel<<<nodeBlocks, 128, 0, stream>>>(agg, x, deg, W1l, b1, W1r, h);

    // Layer 2 (reuse agg buffer)
    hipMemsetAsync(agg, 0, aggBytes, stream);
    scatter_kernel<<<scatterBlocks, 256, 0, stream>>>(h, src, dst, agg, nullptr, E);
    layer2_kernel<<<nodeBlocks, 64, 0, stream>>>(agg, h, deg, W2l, b2, W2r, out);
}

// Round 2
// 996.462 us; speedup vs baseline: 5.9652x; 5.9652x over previous
//
#include <hip/hip_runtime.h>
#include <hip/hip_bf16.h>

#define N_NODES 100000

// ===========================================================================
// CSR build: histogram dst -> exclusive scan -> scatter src ids into slots.
// ===========================================================================
__global__ __launch_bounds__(256) void hist_kernel(
    const int* __restrict__ dst, int* __restrict__ counts, int E)
{
    int i = blockIdx.x * 256 + threadIdx.x;
    if (i < E) atomicAdd(&counts[dst[i]], 1);
}

// Single-block exclusive scan of `counts[0..n)` into row_ptr[0..n], n=100k.
__global__ __launch_bounds__(1024) void scan_kernel(
    const int* __restrict__ counts, int* __restrict__ row_ptr, int n)
{
    __shared__ int part[1024];
    int t = threadIdx.x;
    int chunk = (n + 1023) >> 10;          // 98
    int start = t * chunk;
    int end = min(start + chunk, n);
    int sum = 0;
    for (int i = start; i < end; i++) sum += counts[i];
    part[t] = sum;
    __syncthreads();
    // Hillis-Steele inclusive scan over the 1024 partials.
    for (int off = 1; off < 1024; off <<= 1) {
        int v = 0;
        if (t >= off) v = part[t - off];
        __syncthreads();
        if (t >= off) part[t] += v;
        __syncthreads();
    }
    int prefix = (t == 0) ? 0 : part[t - 1];
    for (int i = start; i < end; i++) { row_ptr[i] = prefix; prefix += counts[i]; }
    if (t == 1023) row_ptr[n] = part[1023];
}

__global__ __launch_bounds__(256) void fill_kernel(
    const int* __restrict__ src, const int* __restrict__ dst,
    int* __restrict__ cursor, int* __restrict__ edge_src, int E)
{
    int i = blockIdx.x * 256 + threadIdx.x;
    if (i < E) {
        int d = dst[i];
        int pos = atomicAdd(&cursor[d], 1);
        edge_src[pos] = src[i];
    }
}

// ===========================================================================
// Gather-based mean aggregation. L = lanes per node = D/4 (float4 per lane).
// Output is already divided by max(deg,1) (deg==0 rows come out 0).
// ===========================================================================
template<int L>
__global__ __launch_bounds__(256) void gather_agg_kernel(
    const float* __restrict__ feat, const int* __restrict__ edge_src,
    const int* __restrict__ row_ptr, float* __restrict__ aggOut)
{
    int tid = blockIdx.x * 256 + threadIdx.x;
    int node = tid / L;
    int q = tid % L;
    if (node >= N_NODES) return;
    int beg = row_ptr[node];
    int end = row_ptr[node + 1];
    const float4* f4 = (const float4*)feat;
    float4 acc = make_float4(0.f, 0.f, 0.f, 0.f);
    int e = beg;
    for (; e + 2 <= end; e += 2) {
        int s0 = edge_src[e];
        int s1 = edge_src[e + 1];
        float4 v0 = f4[(size_t)s0 * L + q];
        float4 v1 = f4[(size_t)s1 * L + q];
        acc.x += v0.x + v1.x;
        acc.y += v0.y + v1.y;
        acc.z += v0.z + v1.z;
        acc.w += v0.w + v1.w;
    }
    if (e < end) {
        int s0 = edge_src[e];
        float4 v0 = f4[(size_t)s0 * L + q];
        acc.x += v0.x; acc.y += v0.y; acc.z += v0.z; acc.w += v0.w;
    }
    int deg = end - beg;
    float inv = (deg > 0) ? 1.0f / (float)deg : 0.0f;
    acc.x *= inv; acc.y *= inv; acc.z *= inv; acc.w *= inv;
    ((float4*)aggOut)[(size_t)node * L + q] = acc;
}

// ===========================================================================
// Layer 1: h[n,j] = relu( agg1[n,:] . W1l[j,:] + b1[j] + x[n,:] . W1r[j,:] )
// agg1 is pre-divided by degree. 8 nodes/block, 128 threads (thread j = out).
// ===========================================================================
__global__ __launch_bounds__(128) void layer1_kernel(
    const float* __restrict__ agg, const float* __restrict__ x,
    const float* __restrict__ W1l, const float* __restrict__ b1,
    const float* __restrict__ W1r, float* __restrict__ h)
{
    __shared__ float a_s[8][128];
    __shared__ float x_s[8][128];
    int node0 = blockIdx.x * 8;

    for (int i = threadIdx.x; i < 8 * 128; i += 128) {
        int k = i >> 7;
        int f = i & 127;
        int n = node0 + k;
        float av = 0.0f, xv = 0.0f;
        if (n < N_NODES) {
            av = agg[(size_t)n * 128 + f];
            xv = x[(size_t)n * 128 + f];
        }
        a_s[k][f] = av;
        x_s[k][f] = xv;
    }
    __syncthreads();

    int j = threadIdx.x;
    float acc[8];
    float bv = b1[j];
    #pragma unroll
    for (int k = 0; k < 8; k++) acc[k] = bv;

    const float4* Wl4 = (const float4*)(W1l + (size_t)j * 128);
    const float4* Wr4 = (const float4*)(W1r + (size_t)j * 128);
    for (int f4 = 0; f4 < 32; f4++) {
        float4 wl = Wl4[f4];
        float4 wr = Wr4[f4];
        int f = f4 * 4;
        #pragma unroll
        for (int k = 0; k < 8; k++) {
            acc[k] += a_s[k][f + 0] * wl.x + a_s[k][f + 1] * wl.y
                    + a_s[k][f + 2] * wl.z + a_s[k][f + 3] * wl.w
                    + x_s[k][f + 0] * wr.x + x_s[k][f + 1] * wr.y
                    + x_s[k][f + 2] * wr.z + x_s[k][f + 3] * wr.w;
        }
    }

    #pragma unroll
    for (int k = 0; k < 8; k++) {
        int n = node0 + k;
        if (n < N_NODES) h[(size_t)n * 128 + j] = fmaxf(acc[k], 0.0f);
    }
}

// ===========================================================================
// g2 = h @ W2l.T   [N,64]. 8 nodes/block, 64 threads (thread c = class).
// (Aggregation commutes with the linear map, so we aggregate g2 afterwards —
//  halves the layer-2 gather payload.)
// ===========================================================================
__global__ __launch_bounds__(64) void g2_kernel(
    const float* __restrict__ h, const float* __restrict__ W2l,
    float* __restrict__ g2)
{
    __shared__ float h_s[8][128];
    int node0 = blockIdx.x * 8;

    for (int i = threadIdx.x; i < 8 * 128; i += 64) {
        int k = i >> 7;
        int f = i & 127;
        int n = node0 + k;
        h_s[k][f] = (n < N_NODES) ? h[(size_t)n * 128 + f] : 0.0f;
    }
    __syncthreads();

    int c = threadIdx.x;
    float acc[8];
    #pragma unroll
    for (int k = 0; k < 8; k++) acc[k] = 0.0f;

    const float4* W4 = (const float4*)(W2l + (size_t)c * 128);
    for (int f4 = 0; f4 < 32; f4++) {
        float4 w = W4[f4];
        int f = f4 * 4;
        #pragma unroll
        for (int k = 0; k < 8; k++) {
            acc[k] += h_s[k][f + 0] * w.x + h_s[k][f + 1] * w.y
                    + h_s[k][f + 2] * w.z + h_s[k][f + 3] * w.w;
        }
    }

    #pragma unroll
    for (int k = 0; k < 8; k++) {
        int n = node0 + k;
        if (n < N_NODES) g2[(size_t)n * 64 + c] = acc[k];
    }
}

// ===========================================================================
// Final: out[n,c] = logsoftmax_c( agg2[n,c] + b2[c] + h[n,:] . W2r[c,:] )
// agg2 pre-divided by degree. 8 nodes/block, 64 threads (one wave).
// ===========================================================================
__global__ __launch_bounds__(64) void final_kernel(
    const float* __restrict__ agg2, const float* __restrict__ h,
    const float* __restrict__ W2r, const float* __restrict__ b2,
    float* __restrict__ out)
{
    __shared__ float h_s[8][128];
    int node0 = blockIdx.x * 8;

    for (int i = threadIdx.x; i < 8 * 128; i += 64) {
        int k = i >> 7;
        int f = i & 127;
        int n = node0 + k;
        h_s[k][f] = (n < N_NODES) ? h[(size_t)n * 128 + f] : 0.0f;
    }
    __syncthreads();

    int c = threadIdx.x;  // 0..63
    float acc[8];
    float bv = b2[c];
    #pragma unroll
    for (int k = 0; k < 8; k++) {
        int n = node0 + k;
        acc[k] = bv + ((n < N_NODES) ? agg2[(size_t)n * 64 + c] : 0.0f);
    }

    const float4* W4 = (const float4*)(W2r + (size_t)c * 128);
    for (int f4 = 0; f4 < 32; f4++) {
        float4 w = W4[f4];
        int f = f4 * 4;
        #pragma unroll
        for (int k = 0; k < 8; k++) {
            acc[k] += h_s[k][f + 0] * w.x + h_s[k][f + 1] * w.y
                    + h_s[k][f + 2] * w.z + h_s[k][f + 3] * w.w;
        }
    }

    // log_softmax over 64 classes = 64 lanes of this wave.
    #pragma unroll
    for (int k = 0; k < 8; k++) {
        float v = acc[k];
        float m = v;
        #pragma unroll
        for (int off = 1; off < 64; off <<= 1)
            m = fmaxf(m, __shfl_xor(m, off, 64));
        float e = expf(v - m);
        float s = e;
        #pragma unroll
        for (int off = 1; off < 64; off <<= 1)
            s += __shfl_xor(s, off, 64);
        int n = node0 + k;
        if (n < N_NODES) out[(size_t)n * 64 + c] = v - m - logf(s);
    }
}

// ===========================================================================
extern "C" void kernel_launch(void* const* d_in, const int* in_sizes, int n_in,
                              void* d_out, int out_size, void* d_ws, size_t ws_size,
                              hipStream_t stream)
{
    const float* x   = (const float*)d_in[0];
    const int*   ei  = (const int*)d_in[1];
    const float* W1l = (const float*)d_in[2];
    const float* b1  = (const float*)d_in[3];
    const float* W1r = (const float*)d_in[4];
    const float* W2l = (const float*)d_in[5];
    const float* b2  = (const float*)d_in[6];
    const float* W2r = (const float*)d_in[7];
    float* out = (float*)d_out;

    int E = in_sizes[1] / 2;
    const int* src = ei;
    const int* dst = ei + E;

    // Workspace layout (ints then floats):
    //   counts[N] | row_ptr[N+1] | cursor[N] | edge_src[E] |
    //   agg1[N*128] (later reused: g2[N*64] at offset 0, agg2[N*64] after) |
    //   h[N*128]
    char* ws = (char*)d_ws;
    int* counts   = (int*)ws;                       ws += sizeof(int) * N_NODES;
    int* row_ptr  = (int*)ws;                       ws += sizeof(int) * (N_NODES + 1);
    int* cursor   = (int*)ws;                       ws += sizeof(int) * N_NODES;
    int* edge_src = (int*)ws;                       ws += sizeof(int) * (size_t)E;
    float* agg1   = (float*)ws;                     ws += sizeof(float) * (size_t)N_NODES * 128;
    float* h      = (float*)ws;

    float* g2   = agg1;                       // [N,64] — agg1 dead after layer1
    float* agg2 = agg1 + (size_t)N_NODES * 64;

    // --- CSR build ---
    hipMemsetAsync(counts, 0, sizeof(int) * N_NODES, stream);
    hist_kernel<<<(E + 255) / 256, 256, 0, stream>>>(dst, counts, E);
    scan_kernel<<<1, 1024, 0, stream>>>(counts, row_ptr, N_NODES);
    hipMemcpyAsync(cursor, row_ptr, sizeof(int) * N_NODES,
                   hipMemcpyDeviceToDevice, stream);
    fill_kernel<<<(E + 255) / 256, 256, 0, stream>>>(src, dst, cursor, edge_src, E);

    int nodeBlocks8 = (N_NODES + 7) / 8;

    // --- Layer 1 ---
    {
        int threads = N_NODES * 32;  // 32 lanes/node (D=128)
        gather_agg_kernel<32><<<(threads + 255) / 256, 256, 0, stream>>>(
            x, edge_src, row_ptr, agg1);
        layer1_kernel<<<nodeBlocks8, 128, 0, stream>>>(agg1, x, W1l, b1, W1r, h);
    }

    // --- Layer 2 (GEMM-then-aggregate on the left branch) ---
    {
        g2_kernel<<<nodeBlocks8, 64, 0, stream>>>(h, W2l, g2);
        int threads = N_NODES * 16;  // 16 lanes/node (D=64)
        gather_agg_kernel<16><<<(threads + 255) / 256, 256, 0, stream>>>(
            g2, edge_src, row_ptr, agg2);
        final_kernel<<<nodeBlocks8, 64, 0, stream>>>(agg2, h, W2r, b2, out);
    }
}

// Round 3
// 685.954 us; speedup vs baseline: 8.6655x; 1.4527x over previous
//
#include <hip/hip_runtime.h>
#include <hip/hip_bf16.h>

#define N_NODES 100000

typedef __attribute__((ext_vector_type(8))) short short8;     // 8 bf16 (4 VGPRs)
typedef __attribute__((ext_vector_type(8))) unsigned short u16x8;
typedef __attribute__((ext_vector_type(4))) unsigned short u16x4;
typedef __attribute__((ext_vector_type(4))) float floatx4;

__device__ __forceinline__ float b2f(unsigned short u) {
    return __uint_as_float(((unsigned int)u) << 16);
}
__device__ __forceinline__ unsigned short f2b(float f) {   // RNE
    unsigned int u = __float_as_uint(f);
    unsigned int r = u + 0x7FFFu + ((u >> 16) & 1u);
    return (unsigned short)(r >> 16);
}

// ===========================================================================
// Prep: x -> bf16
__global__ __launch_bounds__(256) void cvt_x_kernel(
    const float* __restrict__ x, unsigned short* __restrict__ xb)
{
    int tid = blockIdx.x * 256 + threadIdx.x;       // one float4 per thread
    int total = N_NODES * 32;                        // N*128/4
    if (tid >= total) return;
    float4 v = ((const float4*)x)[tid];
    u16x4 o;
    o.x = f2b(v.x); o.y = f2b(v.y); o.z = f2b(v.z); o.w = f2b(v.w);
    ((u16x4*)xb)[tid] = o;
}

// Prep weights: Wcat1b[128][256] = [W1l | W1r] (K-concat), W2lb[64][128], W2rb[64][128]
__global__ __launch_bounds__(256) void prep_w_kernel(
    const float* __restrict__ W1l, const float* __restrict__ W1r,
    const float* __restrict__ W2l, const float* __restrict__ W2r,
    unsigned short* __restrict__ Wcat1b, unsigned short* __restrict__ W2lb,
    unsigned short* __restrict__ W2rb)
{
    int tid = blockIdx.x * 256 + threadIdx.x;
    if (tid < 32768) {                 // 128 x 256
        int j = tid >> 8, k = tid & 255;
        float v = (k < 128) ? W1l[j * 128 + k] : W1r[j * 128 + (k - 128)];
        Wcat1b[tid] = f2b(v);
    } else if (tid < 32768 + 8192) {
        W2lb[tid - 32768] = f2b(W2l[tid - 32768]);
    } else if (tid < 32768 + 16384) {
        W2rb[tid - 32768 - 8192] = f2b(W2r[tid - 32768 - 8192]);
    }
}

// ===========================================================================
// CSR build
__global__ __launch_bounds__(256) void hist_kernel(
    const int* __restrict__ dst, int* __restrict__ counts, int E)
{
    int i = blockIdx.x * 256 + threadIdx.x;
    if (i < E) atomicAdd(&counts[dst[i]], 1);
}

__global__ __launch_bounds__(1024) void scan_kernel(
    const int* __restrict__ counts, int* __restrict__ row_ptr, int n)
{
    __shared__ int part[1024];
    int t = threadIdx.x;
    int chunk = (n + 1023) >> 10;
    int start = t * chunk;
    int end = min(start + chunk, n);
    int sum = 0;
    for (int i = start; i < end; i++) sum += counts[i];
    part[t] = sum;
    __syncthreads();
    for (int off = 1; off < 1024; off <<= 1) {
        int v = 0;
        if (t >= off) v = part[t - off];
        __syncthreads();
        if (t >= off) part[t] += v;
        __syncthreads();
    }
    int prefix = (t == 0) ? 0 : part[t - 1];
    for (int i = start; i < end; i++) { row_ptr[i] = prefix; prefix += counts[i]; }
    if (t == 1023) row_ptr[n] = part[1023];
}

__global__ __launch_bounds__(256) void fill_kernel(
    const int* __restrict__ src, const int* __restrict__ dst,
    int* __restrict__ cursor, int* __restrict__ edge_src, int E)
{
    int i = blockIdx.x * 256 + threadIdx.x;
    if (i < E) {
        int d = dst[i];
        int pos = atomicAdd(&cursor[d], 1);
        edge_src[pos] = src[i];
    }
}

// ===========================================================================
// bf16 gather mean-aggregation. L lanes/node, 8 bf16 (16B) per lane, D = 8*L.
// fp32 accumulate, output pre-divided by max(deg,1), stored bf16.
template<int L>
__global__ __launch_bounds__(256) void gather_agg_kernel(
    const unsigned short* __restrict__ feat, const int* __restrict__ edge_src,
    const int* __restrict__ row_ptr, unsigned short* __restrict__ aggOut)
{
    int tid = blockIdx.x * 256 + threadIdx.x;
    int node = tid / L;
    int q = tid % L;
    if (node >= N_NODES) return;
    int beg = row_ptr[node];
    int end = row_ptr[node + 1];
    const u16x8* f8 = (const u16x8*)feat;
    float acc[8];
    #pragma unroll
    for (int j = 0; j < 8; j++) acc[j] = 0.0f;
    int e = beg;
    for (; e + 2 <= end; e += 2) {
        int s0 = edge_src[e];
        int s1 = edge_src[e + 1];
        u16x8 v0 = f8[(size_t)s0 * L + q];
        u16x8 v1 = f8[(size_t)s1 * L + q];
        #pragma unroll
        for (int j = 0; j < 8; j++) acc[j] += b2f(v0[j]) + b2f(v1[j]);
    }
    if (e < end) {
        u16x8 v0 = f8[(size_t)edge_src[e] * L + q];
        #pragma unroll
        for (int j = 0; j < 8; j++) acc[j] += b2f(v0[j]);
    }
    int deg = end - beg;
    float inv = (deg > 0) ? 1.0f / (float)deg : 0.0f;
    u16x8 o;
    #pragma unroll
    for (int j = 0; j < 8; j++) o[j] = f2b(acc[j] * inv);
    ((u16x8*)aggOut)[(size_t)node * L + q] = o;
}

// ===========================================================================
// Fused dense block:
//   S = [a1b | xb] @ Wcat1^T + b1       (K=256, 128 outputs)
//   h = relu(S)                          (kept in LDS only)
//   g2 = h @ W2l^T   -> g2b [N,64]      (aggregated afterwards)
//   r2 = h @ W2r^T   -> r2b [N,64]
// Block: 256 threads = 4 waves; wave handles 16 nodes (all outputs).
// MFMA fragment maps (guide §3, HW-verified):
//   A: A[m=lane&15][k=quad*8+j]   B: W[n=lane&15][k=quad*8+j]
//   C/D: col=lane&15, row=quad*4+reg
__global__ __launch_bounds__(256) void fused_l1_kernel(
    const unsigned short* __restrict__ a1b, const unsigned short* __restrict__ xb,
    const unsigned short* __restrict__ Wcat1b, const float* __restrict__ b1,
    const unsigned short* __restrict__ W2lb, const unsigned short* __restrict__ W2rb,
    unsigned short* __restrict__ g2b, unsigned short* __restrict__ r2b)
{
    __shared__ unsigned short h_lds[4][16][136];   // +8 pad: quad reads <=2-way banks

    int wave = threadIdx.x >> 6;
    int lane = threadIdx.x & 63;
    int m    = lane & 15;
    int quad = lane >> 4;
    int node0 = blockIdx.x * 64 + wave * 16;

    int nodeA = node0 + m;
    int nA = (nodeA < N_NODES) ? nodeA : (N_NODES - 1);   // clamp OOB loads

    floatx4 acc[8];
    #pragma unroll
    for (int t = 0; t < 8; t++) acc[t] = (floatx4)(0.0f);

    // ---- layer-1 GEMM: K=256 in 8 steps of 32 ----
    #pragma unroll
    for (int ks = 0; ks < 8; ks++) {
        int k0 = ks * 32 + quad * 8;
        const unsigned short* abase =
            (k0 < 128) ? (a1b + (size_t)nA * 128 + k0)
                       : (xb  + (size_t)nA * 128 + (k0 - 128));
        short8 afrag = *(const short8*)abase;
        #pragma unroll
        for (int t = 0; t < 8; t++) {
            short8 bfrag = *(const short8*)(Wcat1b + (size_t)(t * 16 + m) * 256 + k0);
            acc[t] = __builtin_amdgcn_mfma_f32_16x16x32_bf16(afrag, bfrag, acc[t], 0, 0, 0);
        }
    }

    // ---- epilogue 1: relu(+bias) -> LDS (h in row-major per wave) ----
    #pragma unroll
    for (int t = 0; t < 8; t++) {
        int j = t * 16 + m;
        float bias = b1[j];
        #pragma unroll
        for (int r = 0; r < 4; r++) {
            int row = quad * 4 + r;
            float v = fmaxf(acc[t][r] + bias, 0.0f);
            h_lds[wave][row][j] = f2b(v);
        }
    }
    __syncthreads();   // wave-private region, but cheap and safe

    // ---- fused layer-2 matmuls: g2 = h@W2l^T, r2 = h@W2r^T (K=128) ----
    floatx4 acc2[4], acc3[4];
    #pragma unroll
    for (int t = 0; t < 4; t++) { acc2[t] = (floatx4)(0.0f); acc3[t] = (floatx4)(0.0f); }

    #pragma unroll
    for (int ks = 0; ks < 4; ks++) {
        int k0 = ks * 32 + quad * 8;
        short8 afrag = *(const short8*)&h_lds[wave][m][k0];
        #pragma unroll
        for (int t = 0; t < 4; t++) {
            short8 bl = *(const short8*)(W2lb + (size_t)(t * 16 + m) * 128 + k0);
            acc2[t] = __builtin_amdgcn_mfma_f32_16x16x32_bf16(afrag, bl, acc2[t], 0, 0, 0);
            short8 br = *(const short8*)(W2rb + (size_t)(t * 16 + m) * 128 + k0);
            acc3[t] = __builtin_amdgcn_mfma_f32_16x16x32_bf16(afrag, br, acc3[t], 0, 0, 0);
        }
    }

    #pragma unroll
    for (int t = 0; t < 4; t++) {
        #pragma unroll
        for (int r = 0; r < 4; r++) {
            int n = node0 + quad * 4 + r;
            if (n < N_NODES) {
                g2b[(size_t)n * 64 + t * 16 + m] = f2b(acc2[t][r]);
                r2b[(size_t)n * 64 + t * 16 + m] = f2b(acc3[t][r]);
            }
        }
    }
}

// ===========================================================================
// out[n,c] = logsoftmax_c( a2b[n,c] + b2[c] + r2b[n,c] ), 1 node per wave.
__global__ __launch_bounds__(256) void final_kernel(
    const unsigned short* __restrict__ a2b, const unsigned short* __restrict__ r2b,
    const float* __restrict__ b2, float* __restrict__ out)
{
    int node = blockIdx.x * 4 + (threadIdx.x >> 6);
    if (node >= N_NODES) return;
    int c = threadIdx.x & 63;
    float v = b2[c] + b2f(a2b[(size_t)node * 64 + c]) + b2f(r2b[(size_t)node * 64 + c]);
    float mx = v;
    #pragma unroll
    for (int off = 1; off < 64; off <<= 1)
        mx = fmaxf(mx, __shfl_xor(mx, off, 64));
    float e = expf(v - mx);
    float s = e;
    #pragma unroll
    for (int off = 1; off < 64; off <<= 1)
        s += __shfl_xor(s, off, 64);
    out[(size_t)node * 64 + c] = v - mx - logf(s);
}

// ===========================================================================
extern "C" void kernel_launch(void* const* d_in, const int* in_sizes, int n_in,
                              void* d_out, int out_size, void* d_ws, size_t ws_size,
                              hipStream_t stream)
{
    const float* x   = (const float*)d_in[0];
    const int*   ei  = (const int*)d_in[1];
    const float* W1l = (const float*)d_in[2];
    const float* b1  = (const float*)d_in[3];
    const float* W1r = (const float*)d_in[4];
    const float* W2l = (const float*)d_in[5];
    const float* b2  = (const float*)d_in[6];
    const float* W2r = (const float*)d_in[7];
    float* out = (float*)d_out;

    int E = in_sizes[1] / 2;
    const int* src = ei;
    const int* dst = ei + E;

    // Workspace layout (all 16B-aligned sections)
    char* ws = (char*)d_ws;
    int* counts   = (int*)ws;                ws += ((size_t)N_NODES * 4 + 15) / 16 * 16;
    int* row_ptr  = (int*)ws;                ws += ((size_t)(N_NODES + 1) * 4 + 15) / 16 * 16;
    int* cursor   = (int*)ws;                ws += ((size_t)N_NODES * 4 + 15) / 16 * 16;
    int* edge_src = (int*)ws;                ws += ((size_t)E * 4 + 15) / 16 * 16;
    unsigned short* xb     = (unsigned short*)ws;  ws += (size_t)N_NODES * 128 * 2;
    unsigned short* a1b    = (unsigned short*)ws;  ws += (size_t)N_NODES * 128 * 2;
    unsigned short* g2b    = (unsigned short*)ws;  ws += (size_t)N_NODES * 64 * 2;
    unsigned short* r2b    = (unsigned short*)ws;  ws += (size_t)N_NODES * 64 * 2;
    unsigned short* a2b    = (unsigned short*)ws;  ws += (size_t)N_NODES * 64 * 2;
    unsigned short* Wcat1b = (unsigned short*)ws;  ws += 128 * 256 * 2;
    unsigned short* W2lb   = (unsigned short*)ws;  ws += 64 * 128 * 2;
    unsigned short* W2rb   = (unsigned short*)ws;  ws += 64 * 128 * 2;

    // --- prep (bf16 casts) ---
    cvt_x_kernel<<<(N_NODES * 32 + 255) / 256, 256, 0, stream>>>(x, xb);
    prep_w_kernel<<<(49152 + 255) / 256, 256, 0, stream>>>(
        W1l, W1r, W2l, W2r, Wcat1b, W2lb, W2rb);

    // --- CSR build ---
    hipMemsetAsync(counts, 0, sizeof(int) * N_NODES, stream);
    hist_kernel<<<(E + 255) / 256, 256, 0, stream>>>(dst, counts, E);
    scan_kernel<<<1, 1024, 0, stream>>>(counts, row_ptr, N_NODES);
    hipMemcpyAsync(cursor, row_ptr, sizeof(int) * N_NODES,
                   hipMemcpyDeviceToDevice, stream);
    fill_kernel<<<(E + 255) / 256, 256, 0, stream>>>(src, dst, cursor, edge_src, E);

    // --- layer-1 aggregation (D=128, 16 lanes/node) ---
    gather_agg_kernel<16><<<((size_t)N_NODES * 16 + 255) / 256, 256, 0, stream>>>(
        xb, edge_src, row_ptr, a1b);

    // --- fused dense block: layer1 GEMM + relu + both layer2 matmuls ---
    fused_l1_kernel<<<(N_NODES + 63) / 64, 256, 0, stream>>>(
        a1b, xb, Wcat1b, b1, W2lb, W2rb, g2b, r2b);

    // --- layer-2 aggregation (D=64, 8 lanes/node) ---
    gather_agg_kernel<8><<<((size_t)N_NODES * 8 + 255) / 256, 256, 0, stream>>>(
        g2b, edge_src, row_ptr, a2b);

    // --- bias + residual + log_softmax ---
    final_kernel<<<(N_NODES + 3) / 4, 256, 0, stream>>>(a2b, r2b, b2, out);
}

// Round 4
// 530.626 us; speedup vs baseline: 11.2021x; 1.2927x over previous
//
#include <hip/hip_runtime.h>
#include <hip/hip_bf16.h>

#define N_NODES 100000
#define SCAN_TILE 1024                       // elements per block in scan
#define SCAN_NBLK ((N_NODES + SCAN_TILE - 1) / SCAN_TILE)   // 98

typedef __attribute__((ext_vector_type(8))) short short8;     // 8 bf16 (4 VGPRs)
typedef __attribute__((ext_vector_type(8))) unsigned short u16x8;
typedef __attribute__((ext_vector_type(4))) unsigned short u16x4;
typedef __attribute__((ext_vector_type(4))) float floatx4;

__device__ __forceinline__ float b2f(unsigned short u) {
    return __uint_as_float(((unsigned int)u) << 16);
}
__device__ __forceinline__ unsigned short f2b(float f) {   // RNE
    unsigned int u = __float_as_uint(f);
    unsigned int r = u + 0x7FFFu + ((u >> 16) & 1u);
    return (unsigned short)(r >> 16);
}

// ===========================================================================
// Prep: x -> bf16
__global__ __launch_bounds__(256) void cvt_x_kernel(
    const float* __restrict__ x, unsigned short* __restrict__ xb)
{
    int tid = blockIdx.x * 256 + threadIdx.x;       // one float4 per thread
    int total = N_NODES * 32;                        // N*128/4
    if (tid >= total) return;
    float4 v = ((const float4*)x)[tid];
    u16x4 o;
    o.x = f2b(v.x); o.y = f2b(v.y); o.z = f2b(v.z); o.w = f2b(v.w);
    ((u16x4*)xb)[tid] = o;
}

// Prep weights: Wcat1b[128][256] = [W1l | W1r] (K-concat), W2lb[64][128], W2rb[64][128]
__global__ __launch_bounds__(256) void prep_w_kernel(
    const float* __restrict__ W1l, const float* __restrict__ W1r,
    const float* __restrict__ W2l, const float* __restrict__ W2r,
    unsigned short* __restrict__ Wcat1b, unsigned short* __restrict__ W2lb,
    unsigned short* __restrict__ W2rb)
{
    int tid = blockIdx.x * 256 + threadIdx.x;
    if (tid < 32768) {                 // 128 x 256
        int j = tid >> 8, k = tid & 255;
        float v = (k < 128) ? W1l[j * 128 + k] : W1r[j * 128 + (k - 128)];
        Wcat1b[tid] = f2b(v);
    } else if (tid < 32768 + 8192) {
        W2lb[tid - 32768] = f2b(W2l[tid - 32768]);
    } else if (tid < 32768 + 16384) {
        W2rb[tid - 32768 - 8192] = f2b(W2r[tid - 32768 - 8192]);
    }
}

// ===========================================================================
// CSR build
__global__ __launch_bounds__(256) void hist_kernel(
    const int* __restrict__ dst, int* __restrict__ counts, int E)
{
    int i = blockIdx.x * 256 + threadIdx.x;
    if (i < E) atomicAdd(&counts[dst[i]], 1);
}

// --- device-wide exclusive scan of counts[0..n) -> row_ptr[0..n] + cursor ---
// Phase A: per-block (SCAN_TILE elements) sums.
__global__ __launch_bounds__(256) void scanA_kernel(
    const int* __restrict__ counts, int* __restrict__ blockSums, int n)
{
    int base = blockIdx.x * SCAN_TILE + threadIdx.x * 4;
    int s = 0;
    if (base + 3 < n) {
        int4 v = *(const int4*)(counts + base);
        s = v.x + v.y + v.z + v.w;
    } else {
        for (int i = 0; i < 4; i++) if (base + i < n) s += counts[base + i];
    }
    #pragma unroll
    for (int off = 1; off < 64; off <<= 1) s += __shfl_xor(s, off, 64);
    __shared__ int wsum[4];
    if ((threadIdx.x & 63) == 0) wsum[threadIdx.x >> 6] = s;
    __syncthreads();
    if (threadIdx.x == 0)
        blockSums[blockIdx.x] = wsum[0] + wsum[1] + wsum[2] + wsum[3];
}

// Phase B: exclusive scan of the (<=128) block sums in-place; also writes
// row_ptr[n] = total.
__global__ __launch_bounds__(128) void scanB_kernel(
    int* __restrict__ blockSums, int* __restrict__ row_ptr, int numBlocks, int n)
{
    __shared__ int tmp[128];
    int t = threadIdx.x;
    int v = (t < numBlocks) ? blockSums[t] : 0;
    tmp[t] = v;
    __syncthreads();
    for (int off = 1; off < 128; off <<= 1) {
        int u = (t >= off) ? tmp[t - off] : 0;
        __syncthreads();
        tmp[t] += u;
        __syncthreads();
    }
    if (t < numBlocks) blockSums[t] = (t == 0) ? 0 : tmp[t - 1];
    if (t == 0) row_ptr[n] = tmp[numBlocks - 1];
}

// Phase C: in-block exclusive scan + block offset -> row_ptr and cursor.
__global__ __launch_bounds__(256) void scanC_kernel(
    const int* __restrict__ counts, const int* __restrict__ blockSums,
    int* __restrict__ row_ptr, int* __restrict__ cursor, int n)
{
    int t = threadIdx.x;
    int base = blockIdx.x * SCAN_TILE + t * 4;
    int v0 = 0, v1 = 0, v2 = 0, v3 = 0;
    if (base + 3 < n) {
        int4 v = *(const int4*)(counts + base);
        v0 = v.x; v1 = v.y; v2 = v.z; v3 = v.w;
    } else {
        if (base + 0 < n) v0 = counts[base + 0];
        if (base + 1 < n) v1 = counts[base + 1];
        if (base + 2 < n) v2 = counts[base + 2];
        if (base + 3 < n) v3 = counts[base + 3];
    }
    int s = v0 + v1 + v2 + v3;
    __shared__ int tmp[256];
    tmp[t] = s;
    __syncthreads();
    for (int off = 1; off < 256; off <<= 1) {
        int u = (t >= off) ? tmp[t - off] : 0;
        __syncthreads();
        tmp[t] += u;
        __syncthreads();
    }
    int run = blockSums[blockIdx.x] + ((t == 0) ? 0 : tmp[t - 1]);
    if (base + 0 < n) { row_ptr[base + 0] = run; cursor[base + 0] = run; run += v0; }
    if (base + 1 < n) { row_ptr[base + 1] = run; cursor[base + 1] = run; run += v1; }
    if (base + 2 < n) { row_ptr[base + 2] = run; cursor[base + 2] = run; run += v2; }
    if (base + 3 < n) { row_ptr[base + 3] = run; cursor[base + 3] = run; run += v3; }
}

__global__ __launch_bounds__(256) void fill_kernel(
    const int* __restrict__ src, const int* __restrict__ dst,
    int* __restrict__ cursor, int* __restrict__ edge_src, int E)
{
    int i = blockIdx.x * 256 + threadIdx.x;
    if (i < E) {
        int d = dst[i];
        int pos = atomicAdd(&cursor[d], 1);
        edge_src[pos] = src[i];
    }
}

// ===========================================================================
// bf16 gather mean-aggregation. L lanes/node, 8 bf16 (16B) per lane, D = 8*L.
// fp32 accumulate, output pre-divided by max(deg,1), stored bf16.
template<int L>
__global__ __launch_bounds__(256) void gather_agg_kernel(
    const unsigned short* __restrict__ feat, const int* __restrict__ edge_src,
    const int* __restrict__ row_ptr, unsigned short* __restrict__ aggOut)
{
    int tid = blockIdx.x * 256 + threadIdx.x;
    int node = tid / L;
    int q = tid % L;
    if (node >= N_NODES) return;
    int beg = row_ptr[node];
    int end = row_ptr[node + 1];
    const u16x8* f8 = (const u16x8*)feat;
    float acc[8];
    #pragma unroll
    for (int j = 0; j < 8; j++) acc[j] = 0.0f;
    int e = beg;
    for (; e + 2 <= end; e += 2) {
        int s0 = edge_src[e];
        int s1 = edge_src[e + 1];
        u16x8 v0 = f8[(size_t)s0 * L + q];
        u16x8 v1 = f8[(size_t)s1 * L + q];
        #pragma unroll
        for (int j = 0; j < 8; j++) acc[j] += b2f(v0[j]) + b2f(v1[j]);
    }
    if (e < end) {
        u16x8 v0 = f8[(size_t)edge_src[e] * L + q];
        #pragma unroll
        for (int j = 0; j < 8; j++) acc[j] += b2f(v0[j]);
    }
    int deg = end - beg;
    float inv = (deg > 0) ? 1.0f / (float)deg : 0.0f;
    u16x8 o;
    #pragma unroll
    for (int j = 0; j < 8; j++) o[j] = f2b(acc[j] * inv);
    ((u16x8*)aggOut)[(size_t)node * L + q] = o;
}

// ===========================================================================
// Fused dense block:
//   S = [a1b | xb] @ Wcat1^T + b1       (K=256, 128 outputs)
//   h = relu(S)                          (kept in LDS only)
//   g2 = h @ W2l^T   -> g2b [N,64]
//   r2 = h @ W2r^T   -> r2b [N,64]
// Block: 256 threads = 4 waves; wave handles 16 nodes (all outputs).
__global__ __launch_bounds__(256) void fused_l1_kernel(
    const unsigned short* __restrict__ a1b, const unsigned short* __restrict__ xb,
    const unsigned short* __restrict__ Wcat1b, const float* __restrict__ b1,
    const unsigned short* __restrict__ W2lb, const unsigned short* __restrict__ W2rb,
    unsigned short* __restrict__ g2b, unsigned short* __restrict__ r2b)
{
    __shared__ unsigned short h_lds[4][16][136];   // +8 pad: quad reads <=2-way banks

    int wave = threadIdx.x >> 6;
    int lane = threadIdx.x & 63;
    int m    = lane & 15;
    int quad = lane >> 4;
    int node0 = blockIdx.x * 64 + wave * 16;

    int nodeA = node0 + m;
    int nA = (nodeA < N_NODES) ? nodeA : (N_NODES - 1);   // clamp OOB loads

    floatx4 acc[8];
    #pragma unroll
    for (int t = 0; t < 8; t++) acc[t] = (floatx4)(0.0f);

    // ---- layer-1 GEMM: K=256 in 8 steps of 32 ----
    #pragma unroll
    for (int ks = 0; ks < 8; ks++) {
        int k0 = ks * 32 + quad * 8;
        const unsigned short* abase =
            (k0 < 128) ? (a1b + (size_t)nA * 128 + k0)
                       : (xb  + (size_t)nA * 128 + (k0 - 128));
        short8 afrag = *(const short8*)abase;
        #pragma unroll
        for (int t = 0; t < 8; t++) {
            short8 bfrag = *(const short8*)(Wcat1b + (size_t)(t * 16 + m) * 256 + k0);
            acc[t] = __builtin_amdgcn_mfma_f32_16x16x32_bf16(afrag, bfrag, acc[t], 0, 0, 0);
        }
    }

    // ---- epilogue 1: relu(+bias) -> LDS (h in row-major per wave) ----
    #pragma unroll
    for (int t = 0; t < 8; t++) {
        int j = t * 16 + m;
        float bias = b1[j];
        #pragma unroll
        for (int r = 0; r < 4; r++) {
            int row = quad * 4 + r;
            float v = fmaxf(acc[t][r] + bias, 0.0f);
            h_lds[wave][row][j] = f2b(v);
        }
    }
    __syncthreads();

    // ---- fused layer-2 matmuls: g2 = h@W2l^T, r2 = h@W2r^T (K=128) ----
    floatx4 acc2[4], acc3[4];
    #pragma unroll
    for (int t = 0; t < 4; t++) { acc2[t] = (floatx4)(0.0f); acc3[t] = (floatx4)(0.0f); }

    #pragma unroll
    for (int ks = 0; ks < 4; ks++) {
        int k0 = ks * 32 + quad * 8;
        short8 afrag = *(const short8*)&h_lds[wave][m][k0];
        #pragma unroll
        for (int t = 0; t < 4; t++) {
            short8 bl = *(const short8*)(W2lb + (size_t)(t * 16 + m) * 128 + k0);
            acc2[t] = __builtin_amdgcn_mfma_f32_16x16x32_bf16(afrag, bl, acc2[t], 0, 0, 0);
            short8 br = *(const short8*)(W2rb + (size_t)(t * 16 + m) * 128 + k0);
            acc3[t] = __builtin_amdgcn_mfma_f32_16x16x32_bf16(afrag, br, acc3[t], 0, 0, 0);
        }
    }

    #pragma unroll
    for (int t = 0; t < 4; t++) {
        #pragma unroll
        for (int r = 0; r < 4; r++) {
            int n = node0 + quad * 4 + r;
            if (n < N_NODES) {
                g2b[(size_t)n * 64 + t * 16 + m] = f2b(acc2[t][r]);
                r2b[(size_t)n * 64 + t * 16 + m] = f2b(acc3[t][r]);
            }
        }
    }
}

// ===========================================================================
// out[n,c] = logsoftmax_c( a2b[n,c] + b2[c] + r2b[n,c] ), 1 node per wave.
__global__ __launch_bounds__(256) void final_kernel(
    const unsigned short* __restrict__ a2b, const unsigned short* __restrict__ r2b,
    const float* __restrict__ b2, float* __restrict__ out)
{
    int node = blockIdx.x * 4 + (threadIdx.x >> 6);
    if (node >= N_NODES) return;
    int c = threadIdx.x & 63;
    float v = b2[c] + b2f(a2b[(size_t)node * 64 + c]) + b2f(r2b[(size_t)node * 64 + c]);
    float mx = v;
    #pragma unroll
    for (int off = 1; off < 64; off <<= 1)
        mx = fmaxf(mx, __shfl_xor(mx, off, 64));
    float e = expf(v - mx);
    float s = e;
    #pragma unroll
    for (int off = 1; off < 64; off <<= 1)
        s += __shfl_xor(s, off, 64);
    out[(size_t)node * 64 + c] = v - mx - logf(s);
}

// ===========================================================================
extern "C" void kernel_launch(void* const* d_in, const int* in_sizes, int n_in,
                              void* d_out, int out_size, void* d_ws, size_t ws_size,
                              hipStream_t stream)
{
    const float* x   = (const float*)d_in[0];
    const int*   ei  = (const int*)d_in[1];
    const float* W1l = (const float*)d_in[2];
    const float* b1  = (const float*)d_in[3];
    const float* W1r = (const float*)d_in[4];
    const float* W2l = (const float*)d_in[5];
    const float* b2  = (const float*)d_in[6];
    const float* W2r = (const float*)d_in[7];
    float* out = (float*)d_out;

    int E = in_sizes[1] / 2;
    const int* src = ei;
    const int* dst = ei + E;

    // Workspace layout (all 16B-aligned sections)
    char* ws = (char*)d_ws;
    int* counts    = (int*)ws;               ws += ((size_t)N_NODES * 4 + 15) / 16 * 16;
    int* row_ptr   = (int*)ws;               ws += ((size_t)(N_NODES + 1) * 4 + 15) / 16 * 16;
    int* cursor    = (int*)ws;               ws += ((size_t)N_NODES * 4 + 15) / 16 * 16;
    int* blockSums = (int*)ws;               ws += ((size_t)128 * 4 + 15) / 16 * 16;
    int* edge_src  = (int*)ws;               ws += ((size_t)E * 4 + 15) / 16 * 16;
    unsigned short* xb     = (unsigned short*)ws;  ws += (size_t)N_NODES * 128 * 2;
    unsigned short* a1b    = (unsigned short*)ws;  ws += (size_t)N_NODES * 128 * 2;
    unsigned short* g2b    = (unsigned short*)ws;  ws += (size_t)N_NODES * 64 * 2;
    unsigned short* r2b    = (unsigned short*)ws;  ws += (size_t)N_NODES * 64 * 2;
    unsigned short* a2b    = (unsigned short*)ws;  ws += (size_t)N_NODES * 64 * 2;
    unsigned short* Wcat1b = (unsigned short*)ws;  ws += 128 * 256 * 2;
    unsigned short* W2lb   = (unsigned short*)ws;  ws += 64 * 128 * 2;
    unsigned short* W2rb   = (unsigned short*)ws;  ws += 64 * 128 * 2;

    // --- prep (bf16 casts) ---
    cvt_x_kernel<<<(N_NODES * 32 + 255) / 256, 256, 0, stream>>>(x, xb);
    prep_w_kernel<<<(49152 + 255) / 256, 256, 0, stream>>>(
        W1l, W1r, W2l, W2r, Wcat1b, W2lb, W2rb);

    // --- CSR build ---
    hipMemsetAsync(counts, 0, sizeof(int) * N_NODES, stream);
    hist_kernel<<<(E + 255) / 256, 256, 0, stream>>>(dst, counts, E);
    scanA_kernel<<<SCAN_NBLK, 256, 0, stream>>>(counts, blockSums, N_NODES);
    scanB_kernel<<<1, 128, 0, stream>>>(blockSums, row_ptr, SCAN_NBLK, N_NODES);
    scanC_kernel<<<SCAN_NBLK, 256, 0, stream>>>(counts, blockSums, row_ptr, cursor, N_NODES);
    fill_kernel<<<(E + 255) / 256, 256, 0, stream>>>(src, dst, cursor, edge_src, E);

    // --- layer-1 aggregation (D=128, 16 lanes/node) ---
    gather_agg_kernel<16><<<((size_t)N_NODES * 16 + 255) / 256, 256, 0, stream>>>(
        xb, edge_src, row_ptr, a1b);

    // --- fused dense block: layer1 GEMM + relu + both layer2 matmuls ---
    fused_l1_kernel<<<(N_NODES + 63) / 64, 256, 0, stream>>>(
        a1b, xb, Wcat1b, b1, W2lb, W2rb, g2b, r2b);

    // --- layer-2 aggregation (D=64, 8 lanes/node) ---
    gather_agg_kernel<8><<<((size_t)N_NODES * 8 + 255) / 256, 256, 0, stream>>>(
        g2b, edge_src, row_ptr, a2b);

    // --- bias + residual + log_softmax ---
    final_kernel<<<(N_NODES + 3) / 4, 256, 0, stream>>>(a2b, r2b, b2, out);
}

// Round 5
// 506.989 us; speedup vs baseline: 11.7243x; 1.0466x over previous
//
#include <hip/hip_runtime.h>
#include <hip/hip_bf16.h>

#define N_NODES 100000
#define SCAN_TILE 1024                       // elements per block in scan
#define SCAN_NBLK ((N_NODES + SCAN_TILE - 1) / SCAN_TILE)   // 98

#define FILL_SLICES 16
#define SLICE_W (N_NODES / FILL_SLICES)      // 6250 (exact)
#define FILL_EPT 7                           // edges per thread (registers)

typedef __attribute__((ext_vector_type(8))) short short8;     // 8 bf16 (4 VGPRs)
typedef __attribute__((ext_vector_type(8))) unsigned short u16x8;
typedef __attribute__((ext_vector_type(4))) unsigned short u16x4;
typedef __attribute__((ext_vector_type(4))) float floatx4;

__device__ __forceinline__ float b2f(unsigned short u) {
    return __uint_as_float(((unsigned int)u) << 16);
}
__device__ __forceinline__ unsigned short f2b(float f) {   // RNE
    unsigned int u = __float_as_uint(f);
    unsigned int r = u + 0x7FFFu + ((u >> 16) & 1u);
    return (unsigned short)(r >> 16);
}

// ===========================================================================
// Prep: x -> bf16
__global__ __launch_bounds__(256) void cvt_x_kernel(
    const float* __restrict__ x, unsigned short* __restrict__ xb)
{
    int tid = blockIdx.x * 256 + threadIdx.x;       // one float4 per thread
    int total = N_NODES * 32;                        // N*128/4
    if (tid >= total) return;
    float4 v = ((const float4*)x)[tid];
    u16x4 o;
    o.x = f2b(v.x); o.y = f2b(v.y); o.z = f2b(v.z); o.w = f2b(v.w);
    ((u16x4*)xb)[tid] = o;
}

// Prep weights: Wcat1b[128][256] = [W1l | W1r] (K-concat), W2lb[64][128], W2rb[64][128]
__global__ __launch_bounds__(256) void prep_w_kernel(
    const float* __restrict__ W1l, const float* __restrict__ W1r,
    const float* __restrict__ W2l, const float* __restrict__ W2r,
    unsigned short* __restrict__ Wcat1b, unsigned short* __restrict__ W2lb,
    unsigned short* __restrict__ W2rb)
{
    int tid = blockIdx.x * 256 + threadIdx.x;
    if (tid < 32768) {                 // 128 x 256
        int j = tid >> 8, k = tid & 255;
        float v = (k < 128) ? W1l[j * 128 + k] : W1r[j * 128 + (k - 128)];
        Wcat1b[tid] = f2b(v);
    } else if (tid < 32768 + 8192) {
        W2lb[tid - 32768] = f2b(W2l[tid - 32768]);
    } else if (tid < 32768 + 16384) {
        W2rb[tid - 32768 - 8192] = f2b(W2r[tid - 32768 - 8192]);
    }
}

// ===========================================================================
// CSR build
__global__ __launch_bounds__(256) void hist_kernel(
    const int* __restrict__ dst, int* __restrict__ counts, int E)
{
    int i = blockIdx.x * 256 + threadIdx.x;
    if (i < E) atomicAdd(&counts[dst[i]], 1);
}

// --- device-wide exclusive scan of counts[0..n) -> row_ptr[0..n] + cursor ---
// Phase A: per-block (SCAN_TILE elements) sums.
__global__ __launch_bounds__(256) void scanA_kernel(
    const int* __restrict__ counts, int* __restrict__ blockSums, int n)
{
    int base = blockIdx.x * SCAN_TILE + threadIdx.x * 4;
    int s = 0;
    if (base + 3 < n) {
        int4 v = *(const int4*)(counts + base);
        s = v.x + v.y + v.z + v.w;
    } else {
        for (int i = 0; i < 4; i++) if (base + i < n) s += counts[base + i];
    }
    #pragma unroll
    for (int off = 1; off < 64; off <<= 1) s += __shfl_xor(s, off, 64);
    __shared__ int wsum[4];
    if ((threadIdx.x & 63) == 0) wsum[threadIdx.x >> 6] = s;
    __syncthreads();
    if (threadIdx.x == 0)
        blockSums[blockIdx.x] = wsum[0] + wsum[1] + wsum[2] + wsum[3];
}

// Phase B: exclusive scan of the (<=128) block sums in-place; also writes
// row_ptr[n] = total.
__global__ __launch_bounds__(128) void scanB_kernel(
    int* __restrict__ blockSums, int* __restrict__ row_ptr, int numBlocks, int n)
{
    __shared__ int tmp[128];
    int t = threadIdx.x;
    int v = (t < numBlocks) ? blockSums[t] : 0;
    tmp[t] = v;
    __syncthreads();
    for (int off = 1; off < 128; off <<= 1) {
        int u = (t >= off) ? tmp[t - off] : 0;
        __syncthreads();
        tmp[t] += u;
        __syncthreads();
    }
    if (t < numBlocks) blockSums[t] = (t == 0) ? 0 : tmp[t - 1];
    if (t == 0) row_ptr[n] = tmp[numBlocks - 1];
}

// Phase C: in-block exclusive scan + block offset -> row_ptr and cursor.
__global__ __launch_bounds__(256) void scanC_kernel(
    const int* __restrict__ counts, const int* __restrict__ blockSums,
    int* __restrict__ row_ptr, int* __restrict__ cursor, int n)
{
    int t = threadIdx.x;
    int base = blockIdx.x * SCAN_TILE + t * 4;
    int v0 = 0, v1 = 0, v2 = 0, v3 = 0;
    if (base + 3 < n) {
        int4 v = *(const int4*)(counts + base);
        v0 = v.x; v1 = v.y; v2 = v.z; v3 = v.w;
    } else {
        if (base + 0 < n) v0 = counts[base + 0];
        if (base + 1 < n) v1 = counts[base + 1];
        if (base + 2 < n) v2 = counts[base + 2];
        if (base + 3 < n) v3 = counts[base + 3];
    }
    int s = v0 + v1 + v2 + v3;
    __shared__ int tmp[256];
    tmp[t] = s;
    __syncthreads();
    for (int off = 1; off < 256; off <<= 1) {
        int u = (t >= off) ? tmp[t - off] : 0;
        __syncthreads();
        tmp[t] += u;
        __syncthreads();
    }
    int run = blockSums[blockIdx.x] + ((t == 0) ? 0 : tmp[t - 1]);
    if (base + 0 < n) { row_ptr[base + 0] = run; cursor[base + 0] = run; run += v0; }
    if (base + 1 < n) { row_ptr[base + 1] = run; cursor[base + 1] = run; run += v1; }
    if (base + 2 < n) { row_ptr[base + 2] = run; cursor[base + 2] = run; run += v2; }
    if (base + 3 < n) { row_ptr[base + 3] = run; cursor[base + 3] = run; run += v3; }
}

// ===========================================================================
// Slice-localized CSR fill. Persistent kernel: every block resident; each
// thread owns FILL_EPT edges in registers (single coalesced read), then all
// waves sweep 16 dst-slices in soft lockstep. Active write window per slice:
// ~400 KB of edge_src + 25 KB of cursor -> L2-resident, full-line write-backs
// (kills the 16x write amplification of the naive random scatter).
__global__ __launch_bounds__(1024) void fill_kernel(
    const int* __restrict__ src, const int* __restrict__ dst,
    int* __restrict__ cursor, int* __restrict__ edge_src, int E)
{
    int T = gridDim.x * 1024;
    int tid = blockIdx.x * 1024 + threadIdx.x;

    int es[FILL_EPT], ed[FILL_EPT];
    #pragma unroll
    for (int j = 0; j < FILL_EPT; j++) {
        long long i = (long long)tid + (long long)j * T;
        bool v = (i < E);
        es[j] = v ? src[i] : 0;
        ed[j] = v ? dst[i] : -1;     // -1 never falls in any slice
    }

    for (int p = 0; p < FILL_SLICES; p++) {
        int lo = p * SLICE_W;
        int hi = lo + SLICE_W;
        #pragma unroll
        for (int j = 0; j < FILL_EPT; j++) {
            if (ed[j] >= lo && ed[j] < hi) {
                int pos = atomicAdd(&cursor[ed[j]], 1);
                edge_src[pos] = es[j];
            }
        }
    }
}

// ===========================================================================
// bf16 gather mean-aggregation. L lanes/node, 8 bf16 (16B) per lane, D = 8*L.
// fp32 accumulate, output pre-divided by max(deg,1), stored bf16.
template<int L>
__global__ __launch_bounds__(256) void gather_agg_kernel(
    const unsigned short* __restrict__ feat, const int* __restrict__ edge_src,
    const int* __restrict__ row_ptr, unsigned short* __restrict__ aggOut)
{
    int tid = blockIdx.x * 256 + threadIdx.x;
    int node = tid / L;
    int q = tid % L;
    if (node >= N_NODES) return;
    int beg = row_ptr[node];
    int end = row_ptr[node + 1];
    const u16x8* f8 = (const u16x8*)feat;
    float acc[8];
    #pragma unroll
    for (int j = 0; j < 8; j++) acc[j] = 0.0f;
    int e = beg;
    for (; e + 2 <= end; e += 2) {
        int s0 = edge_src[e];
        int s1 = edge_src[e + 1];
        u16x8 v0 = f8[(size_t)s0 * L + q];
        u16x8 v1 = f8[(size_t)s1 * L + q];
        #pragma unroll
        for (int j = 0; j < 8; j++) acc[j] += b2f(v0[j]) + b2f(v1[j]);
    }
    if (e < end) {
        u16x8 v0 = f8[(size_t)edge_src[e] * L + q];
        #pragma unroll
        for (int j = 0; j < 8; j++) acc[j] += b2f(v0[j]);
    }
    int deg = end - beg;
    float inv = (deg > 0) ? 1.0f / (float)deg : 0.0f;
    u16x8 o;
    #pragma unroll
    for (int j = 0; j < 8; j++) o[j] = f2b(acc[j] * inv);
    ((u16x8*)aggOut)[(size_t)node * L + q] = o;
}

// ===========================================================================
// Fused dense block:
//   S = [a1b | xb] @ Wcat1^T + b1       (K=256, 128 outputs)
//   h = relu(S)                          (kept in LDS only)
//   g2 = h @ W2l^T   -> g2b [N,64]
//   r2 = h @ W2r^T   -> r2b [N,64]
// Block: 256 threads = 4 waves; wave handles 16 nodes (all outputs).
__global__ __launch_bounds__(256) void fused_l1_kernel(
    const unsigned short* __restrict__ a1b, const unsigned short* __restrict__ xb,
    const unsigned short* __restrict__ Wcat1b, const float* __restrict__ b1,
    const unsigned short* __restrict__ W2lb, const unsigned short* __restrict__ W2rb,
    unsigned short* __restrict__ g2b, unsigned short* __restrict__ r2b)
{
    __shared__ unsigned short h_lds[4][16][136];   // +8 pad: quad reads <=2-way banks

    int wave = threadIdx.x >> 6;
    int lane = threadIdx.x & 63;
    int m    = lane & 15;
    int quad = lane >> 4;
    int node0 = blockIdx.x * 64 + wave * 16;

    int nodeA = node0 + m;
    int nA = (nodeA < N_NODES) ? nodeA : (N_NODES - 1);   // clamp OOB loads

    floatx4 acc[8];
    #pragma unroll
    for (int t = 0; t < 8; t++) acc[t] = (floatx4)(0.0f);

    // ---- layer-1 GEMM: K=256 in 8 steps of 32 ----
    #pragma unroll
    for (int ks = 0; ks < 8; ks++) {
        int k0 = ks * 32 + quad * 8;
        const unsigned short* abase =
            (k0 < 128) ? (a1b + (size_t)nA * 128 + k0)
                       : (xb  + (size_t)nA * 128 + (k0 - 128));
        short8 afrag = *(const short8*)abase;
        #pragma unroll
        for (int t = 0; t < 8; t++) {
            short8 bfrag = *(const short8*)(Wcat1b + (size_t)(t * 16 + m) * 256 + k0);
            acc[t] = __builtin_amdgcn_mfma_f32_16x16x32_bf16(afrag, bfrag, acc[t], 0, 0, 0);
        }
    }

    // ---- epilogue 1: relu(+bias) -> LDS (h in row-major per wave) ----
    #pragma unroll
    for (int t = 0; t < 8; t++) {
        int j = t * 16 + m;
        float bias = b1[j];
        #pragma unroll
        for (int r = 0; r < 4; r++) {
            int row = quad * 4 + r;
            float v = fmaxf(acc[t][r] + bias, 0.0f);
            h_lds[wave][row][j] = f2b(v);
        }
    }
    __syncthreads();

    // ---- fused layer-2 matmuls: g2 = h@W2l^T, r2 = h@W2r^T (K=128) ----
    floatx4 acc2[4], acc3[4];
    #pragma unroll
    for (int t = 0; t < 4; t++) { acc2[t] = (floatx4)(0.0f); acc3[t] = (floatx4)(0.0f); }

    #pragma unroll
    for (int ks = 0; ks < 4; ks++) {
        int k0 = ks * 32 + quad * 8;
        short8 afrag = *(const short8*)&h_lds[wave][m][k0];
        #pragma unroll
        for (int t = 0; t < 4; t++) {
            short8 bl = *(const short8*)(W2lb + (size_t)(t * 16 + m) * 128 + k0);
            acc2[t] = __builtin_amdgcn_mfma_f32_16x16x32_bf16(afrag, bl, acc2[t], 0, 0, 0);
            short8 br = *(const short8*)(W2rb + (size_t)(t * 16 + m) * 128 + k0);
            acc3[t] = __builtin_amdgcn_mfma_f32_16x16x32_bf16(afrag, br, acc3[t], 0, 0, 0);
        }
    }

    #pragma unroll
    for (int t = 0; t < 4; t++) {
        #pragma unroll
        for (int r = 0; r < 4; r++) {
            int n = node0 + quad * 4 + r;
            if (n < N_NODES) {
                g2b[(size_t)n * 64 + t * 16 + m] = f2b(acc2[t][r]);
                r2b[(size_t)n * 64 + t * 16 + m] = f2b(acc3[t][r]);
            }
        }
    }
}

// ===========================================================================
// out[n,c] = logsoftmax_c( a2b[n,c] + b2[c] + r2b[n,c] ), 1 node per wave.
__global__ __launch_bounds__(256) void final_kernel(
    const unsigned short* __restrict__ a2b, const unsigned short* __restrict__ r2b,
    const float* __restrict__ b2, float* __restrict__ out)
{
    int node = blockIdx.x * 4 + (threadIdx.x >> 6);
    if (node >= N_NODES) return;
    int c = threadIdx.x & 63;
    float v = b2[c] + b2f(a2b[(size_t)node * 64 + c]) + b2f(r2b[(size_t)node * 64 + c]);
    float mx = v;
    #pragma unroll
    for (int off = 1; off < 64; off <<= 1)
        mx = fmaxf(mx, __shfl_xor(mx, off, 64));
    float e = expf(v - mx);
    float s = e;
    #pragma unroll
    for (int off = 1; off < 64; off <<= 1)
        s += __shfl_xor(s, off, 64);
    out[(size_t)node * 64 + c] = v - mx - logf(s);
}

// ===========================================================================
extern "C" void kernel_launch(void* const* d_in, const int* in_sizes, int n_in,
                              void* d_out, int out_size, void* d_ws, size_t ws_size,
                              hipStream_t stream)
{
    const float* x   = (const float*)d_in[0];
    const int*   ei  = (const int*)d_in[1];
    const float* W1l = (const float*)d_in[2];
    const float* b1  = (const float*)d_in[3];
    const float* W1r = (const float*)d_in[4];
    const float* W2l = (const float*)d_in[5];
    const float* b2  = (const float*)d_in[6];
    const float* W2r = (const float*)d_in[7];
    float* out = (float*)d_out;

    int E = in_sizes[1] / 2;
    const int* src = ei;
    const int* dst = ei + E;

    // Workspace layout (all 16B-aligned sections)
    char* ws = (char*)d_ws;
    int* counts    = (int*)ws;               ws += ((size_t)N_NODES * 4 + 15) / 16 * 16;
    int* row_ptr   = (int*)ws;               ws += ((size_t)(N_NODES + 1) * 4 + 15) / 16 * 16;
    int* cursor    = (int*)ws;               ws += ((size_t)N_NODES * 4 + 15) / 16 * 16;
    int* blockSums = (int*)ws;               ws += ((size_t)128 * 4 + 15) / 16 * 16;
    int* edge_src  = (int*)ws;               ws += ((size_t)E * 4 + 15) / 16 * 16;
    unsigned short* xb     = (unsigned short*)ws;  ws += (size_t)N_NODES * 128 * 2;
    unsigned short* a1b    = (unsigned short*)ws;  ws += (size_t)N_NODES * 128 * 2;
    unsigned short* g2b    = (unsigned short*)ws;  ws += (size_t)N_NODES * 64 * 2;
    unsigned short* r2b    = (unsigned short*)ws;  ws += (size_t)N_NODES * 64 * 2;
    unsigned short* a2b    = (unsigned short*)ws;  ws += (size_t)N_NODES * 64 * 2;
    unsigned short* Wcat1b = (unsigned short*)ws;  ws += 128 * 256 * 2;
    unsigned short* W2lb   = (unsigned short*)ws;  ws += 64 * 128 * 2;
    unsigned short* W2rb   = (unsigned short*)ws;  ws += 64 * 128 * 2;

    // --- prep (bf16 casts) ---
    cvt_x_kernel<<<(N_NODES * 32 + 255) / 256, 256, 0, stream>>>(x, xb);
    prep_w_kernel<<<(49152 + 255) / 256, 256, 0, stream>>>(
        W1l, W1r, W2l, W2r, Wcat1b, W2lb, W2rb);

    // --- CSR build ---
    hipMemsetAsync(counts, 0, sizeof(int) * N_NODES, stream);
    hist_kernel<<<(E + 255) / 256, 256, 0, stream>>>(dst, counts, E);
    scanA_kernel<<<SCAN_NBLK, 256, 0, stream>>>(counts, blockSums, N_NODES);
    scanB_kernel<<<1, 128, 0, stream>>>(blockSums, row_ptr, SCAN_NBLK, N_NODES);
    scanC_kernel<<<SCAN_NBLK, 256, 0, stream>>>(counts, blockSums, row_ptr, cursor, N_NODES);
    {
        int fillBlocks = (E + 1024 * FILL_EPT - 1) / (1024 * FILL_EPT);  // 224 for E=1.6M
        fill_kernel<<<fillBlocks, 1024, 0, stream>>>(src, dst, cursor, edge_src, E);
    }

    // --- layer-1 aggregation (D=128, 16 lanes/node) ---
    gather_agg_kernel<16><<<((size_t)N_NODES * 16 + 255) / 256, 256, 0, stream>>>(
        xb, edge_src, row_ptr, a1b);

    // --- fused dense block: layer1 GEMM + relu + both layer2 matmuls ---
    fused_l1_kernel<<<(N_NODES + 63) / 64, 256, 0, stream>>>(
        a1b, xb, Wcat1b, b1, W2lb, W2rb, g2b, r2b);

    // --- layer-2 aggregation (D=64, 8 lanes/node) ---
    gather_agg_kernel<8><<<((size_t)N_NODES * 8 + 255) / 256, 256, 0, stream>>>(
        g2b, edge_src, row_ptr, a2b);

    // --- bias + residual + log_softmax ---
    final_kernel<<<(N_NODES + 3) / 4, 256, 0, stream>>>(a2b, r2b, b2, out);
}

// Round 6
// 476.290 us; speedup vs baseline: 12.4800x; 1.0645x over previous
//
#include <hip/hip_runtime.h>
#include <hip/hip_bf16.h>

#define N_NODES 100000
#define SCAN_TILE 1024                       // elements per block in scan
#define SCAN_NBLK ((N_NODES + SCAN_TILE - 1) / SCAN_TILE)   // 98

#define FILL_SLICES 16
#define SLICE_W (N_NODES / FILL_SLICES)      // 6250 (exact)
#define FILL_EPT 7                           // edges per thread (registers)

typedef __attribute__((ext_vector_type(8))) short short8;     // 8 bf16 (4 VGPRs)
typedef __attribute__((ext_vector_type(8))) unsigned short u16x8;
typedef __attribute__((ext_vector_type(4))) unsigned short u16x4;
typedef __attribute__((ext_vector_type(4))) float floatx4;

__device__ __forceinline__ float b2f(unsigned short u) {
    return __uint_as_float(((unsigned int)u) << 16);
}
__device__ __forceinline__ unsigned short f2b(float f) {   // RNE
    unsigned int u = __float_as_uint(f);
    unsigned int r = u + 0x7FFFu + ((u >> 16) & 1u);
    return (unsigned short)(r >> 16);
}

// ===========================================================================
// Prep: x -> bf16
__global__ __launch_bounds__(256) void cvt_x_kernel(
    const float* __restrict__ x, unsigned short* __restrict__ xb)
{
    int tid = blockIdx.x * 256 + threadIdx.x;       // one float4 per thread
    int total = N_NODES * 32;                        // N*128/4
    if (tid >= total) return;
    float4 v = ((const float4*)x)[tid];
    u16x4 o;
    o.x = f2b(v.x); o.y = f2b(v.y); o.z = f2b(v.z); o.w = f2b(v.w);
    ((u16x4*)xb)[tid] = o;
}

// Prep weights into MFMA *fragment-major* layout: a wave's B-frag for
// (ks, t) sits at ((ks*T + t)*64 + lane)*8 bf16 — lane i reads base+i*16B,
// i.e. ONE coalesced 1 KB load instead of 16 scattered 64 B segments.
//   Wc1f:  layer-1 [Wl|Wr] K-concat, ks in [0,8), t in [0,8)
//   W2lf/W2rf: layer-2,               ks in [0,4), t in [0,4)
// Fragment element: row = t*16 + (lane&15), k = ks*32 + (lane>>4)*8 + j.
__global__ __launch_bounds__(256) void prep_w_kernel(
    const float* __restrict__ W1l, const float* __restrict__ W1r,
    const float* __restrict__ W2l, const float* __restrict__ W2r,
    unsigned short* __restrict__ Wc1f, unsigned short* __restrict__ W2lf,
    unsigned short* __restrict__ W2rf)
{
    int tid = blockIdx.x * 256 + threadIdx.x;
    if (tid < 32768) {                 // 8 ks * 8 t * 64 lane * 8 j
        int j = tid & 7, lane = (tid >> 3) & 63, t = (tid >> 9) & 7, ks = tid >> 12;
        int m = lane & 15, quad = lane >> 4;
        int row = t * 16 + m;
        int k = ks * 32 + quad * 8 + j;
        float v = (k < 128) ? W1l[row * 128 + k] : W1r[row * 128 + (k - 128)];
        Wc1f[tid] = f2b(v);
    } else if (tid < 40960) {          // 4 ks * 4 t * 64 lane * 8 j
        int idx = tid - 32768;
        int j = idx & 7, lane = (idx >> 3) & 63, t = (idx >> 9) & 3, ks = idx >> 11;
        int m = lane & 15, quad = lane >> 4;
        int row = t * 16 + m;
        int k = ks * 32 + quad * 8 + j;
        W2lf[idx] = f2b(W2l[row * 128 + k]);
    } else if (tid < 49152) {
        int idx = tid - 40960;
        int j = idx & 7, lane = (idx >> 3) & 63, t = (idx >> 9) & 3, ks = idx >> 11;
        int m = lane & 15, quad = lane >> 4;
        int row = t * 16 + m;
        int k = ks * 32 + quad * 8 + j;
        W2rf[idx] = f2b(W2r[row * 128 + k]);
    }
}

// ===========================================================================
// CSR build
__global__ __launch_bounds__(256) void hist_kernel(
    const int* __restrict__ dst, int* __restrict__ counts, int E)
{
    int i = blockIdx.x * 256 + threadIdx.x;
    if (i < E) atomicAdd(&counts[dst[i]], 1);
}

// --- device-wide exclusive scan of counts[0..n) -> row_ptr[0..n] + cursor ---
__global__ __launch_bounds__(256) void scanA_kernel(
    const int* __restrict__ counts, int* __restrict__ blockSums, int n)
{
    int base = blockIdx.x * SCAN_TILE + threadIdx.x * 4;
    int s = 0;
    if (base + 3 < n) {
        int4 v = *(const int4*)(counts + base);
        s = v.x + v.y + v.z + v.w;
    } else {
        for (int i = 0; i < 4; i++) if (base + i < n) s += counts[base + i];
    }
    #pragma unroll
    for (int off = 1; off < 64; off <<= 1) s += __shfl_xor(s, off, 64);
    __shared__ int wsum[4];
    if ((threadIdx.x & 63) == 0) wsum[threadIdx.x >> 6] = s;
    __syncthreads();
    if (threadIdx.x == 0)
        blockSums[blockIdx.x] = wsum[0] + wsum[1] + wsum[2] + wsum[3];
}

__global__ __launch_bounds__(128) void scanB_kernel(
    int* __restrict__ blockSums, int* __restrict__ row_ptr, int numBlocks, int n)
{
    __shared__ int tmp[128];
    int t = threadIdx.x;
    int v = (t < numBlocks) ? blockSums[t] : 0;
    tmp[t] = v;
    __syncthreads();
    for (int off = 1; off < 128; off <<= 1) {
        int u = (t >= off) ? tmp[t - off] : 0;
        __syncthreads();
        tmp[t] += u;
        __syncthreads();
    }
    if (t < numBlocks) blockSums[t] = (t == 0) ? 0 : tmp[t - 1];
    if (t == 0) row_ptr[n] = tmp[numBlocks - 1];
}

__global__ __launch_bounds__(256) void scanC_kernel(
    const int* __restrict__ counts, const int* __restrict__ blockSums,
    int* __restrict__ row_ptr, int* __restrict__ cursor, int n)
{
    int t = threadIdx.x;
    int base = blockIdx.x * SCAN_TILE + t * 4;
    int v0 = 0, v1 = 0, v2 = 0, v3 = 0;
    if (base + 3 < n) {
        int4 v = *(const int4*)(counts + base);
        v0 = v.x; v1 = v.y; v2 = v.z; v3 = v.w;
    } else {
        if (base + 0 < n) v0 = counts[base + 0];
        if (base + 1 < n) v1 = counts[base + 1];
        if (base + 2 < n) v2 = counts[base + 2];
        if (base + 3 < n) v3 = counts[base + 3];
    }
    int s = v0 + v1 + v2 + v3;
    __shared__ int tmp[256];
    tmp[t] = s;
    __syncthreads();
    for (int off = 1; off < 256; off <<= 1) {
        int u = (t >= off) ? tmp[t - off] : 0;
        __syncthreads();
        tmp[t] += u;
        __syncthreads();
    }
    int run = blockSums[blockIdx.x] + ((t == 0) ? 0 : tmp[t - 1]);
    if (base + 0 < n) { row_ptr[base + 0] = run; cursor[base + 0] = run; run += v0; }
    if (base + 1 < n) { row_ptr[base + 1] = run; cursor[base + 1] = run; run += v1; }
    if (base + 2 < n) { row_ptr[base + 2] = run; cursor[base + 2] = run; run += v2; }
    if (base + 3 < n) { row_ptr[base + 3] = run; cursor[base + 3] = run; run += v3; }
}

// ===========================================================================
// Slice-localized CSR fill (persistent; kills write amplification).
__global__ __launch_bounds__(1024) void fill_kernel(
    const int* __restrict__ src, const int* __restrict__ dst,
    int* __restrict__ cursor, int* __restrict__ edge_src, int E)
{
    int T = gridDim.x * 1024;
    int tid = blockIdx.x * 1024 + threadIdx.x;

    int es[FILL_EPT], ed[FILL_EPT];
    #pragma unroll
    for (int j = 0; j < FILL_EPT; j++) {
        long long i = (long long)tid + (long long)j * T;
        bool v = (i < E);
        es[j] = v ? src[i] : 0;
        ed[j] = v ? dst[i] : -1;
    }

    for (int p = 0; p < FILL_SLICES; p++) {
        int lo = p * SLICE_W;
        int hi = lo + SLICE_W;
        #pragma unroll
        for (int j = 0; j < FILL_EPT; j++) {
            if (ed[j] >= lo && ed[j] < hi) {
                int pos = atomicAdd(&cursor[ed[j]], 1);
                edge_src[pos] = es[j];
            }
        }
    }
}

// ===========================================================================
// bf16 gather mean-aggregation. L lanes/node, 8 bf16 (16B) per lane, D = 8*L.
template<int L>
__global__ __launch_bounds__(256) void gather_agg_kernel(
    const unsigned short* __restrict__ feat, const int* __restrict__ edge_src,
    const int* __restrict__ row_ptr, unsigned short* __restrict__ aggOut)
{
    int tid = blockIdx.x * 256 + threadIdx.x;
    int node = tid / L;
    int q = tid % L;
    if (node >= N_NODES) return;
    int beg = row_ptr[node];
    int end = row_ptr[node + 1];
    const u16x8* f8 = (const u16x8*)feat;
    float acc[8];
    #pragma unroll
    for (int j = 0; j < 8; j++) acc[j] = 0.0f;
    int e = beg;
    for (; e + 2 <= end; e += 2) {
        int s0 = edge_src[e];
        int s1 = edge_src[e + 1];
        u16x8 v0 = f8[(size_t)s0 * L + q];
        u16x8 v1 = f8[(size_t)s1 * L + q];
        #pragma unroll
        for (int j = 0; j < 8; j++) acc[j] += b2f(v0[j]) + b2f(v1[j]);
    }
    if (e < end) {
        u16x8 v0 = f8[(size_t)edge_src[e] * L + q];
        #pragma unroll
        for (int j = 0; j < 8; j++) acc[j] += b2f(v0[j]);
    }
    int deg = end - beg;
    float inv = (deg > 0) ? 1.0f / (float)deg : 0.0f;
    u16x8 o;
    #pragma unroll
    for (int j = 0; j < 8; j++) o[j] = f2b(acc[j] * inv);
    ((u16x8*)aggOut)[(size_t)node * L + q] = o;
}

// ===========================================================================
// Fused dense block (v2: fragment-major weights, 32 nodes/wave):
//   S = [a1b | xb] @ W1^T + b1 ; h = relu(S) (LDS only)
//   g2 = h @ W2l^T ; r2 = h @ W2r^T
// Block: 256 threads = 4 waves; wave = 32 nodes (two 16-row M-tiles).
__global__ __launch_bounds__(256) void fused_l1_kernel(
    const unsigned short* __restrict__ a1b, const unsigned short* __restrict__ xb,
    const unsigned short* __restrict__ Wc1f, const float* __restrict__ b1,
    const unsigned short* __restrict__ W2lf, const unsigned short* __restrict__ W2rf,
    unsigned short* __restrict__ g2b, unsigned short* __restrict__ r2b)
{
    __shared__ unsigned short h_lds[4][32][136];   // 272 B row stride, 16B aligned

    int wave = threadIdx.x >> 6;
    int lane = threadIdx.x & 63;
    int m    = lane & 15;
    int quad = lane >> 4;
    int node0 = blockIdx.x * 128 + wave * 32;

    int n0 = min(node0 + m,      N_NODES - 1);   // clamp OOB loads
    int n1 = min(node0 + 16 + m, N_NODES - 1);

    floatx4 acc[2][8];
    #pragma unroll
    for (int mt = 0; mt < 2; mt++)
        #pragma unroll
        for (int t = 0; t < 8; t++) acc[mt][t] = (floatx4)(0.0f);

    // ---- layer-1 GEMM: K=256 in 8 steps of 32 ----
    #pragma unroll
    for (int ks = 0; ks < 8; ks++) {
        int k0 = ks * 32 + quad * 8;
        const unsigned short* s = (ks < 4) ? a1b : xb;
        int koff = (ks < 4) ? k0 : (k0 - 128);
        short8 af0 = *(const short8*)(s + (size_t)n0 * 128 + koff);
        short8 af1 = *(const short8*)(s + (size_t)n1 * 128 + koff);
        #pragma unroll
        for (int t = 0; t < 8; t++) {
            short8 bf = *(const short8*)(Wc1f + (((ks * 8 + t) * 64 + lane) << 3));
            acc[0][t] = __builtin_amdgcn_mfma_f32_16x16x32_bf16(af0, bf, acc[0][t], 0, 0, 0);
            acc[1][t] = __builtin_amdgcn_mfma_f32_16x16x32_bf16(af1, bf, acc[1][t], 0, 0, 0);
        }
    }

    // ---- epilogue 1: relu(+bias) -> LDS (h row-major per wave) ----
    #pragma unroll
    for (int t = 0; t < 8; t++) {
        int j = t * 16 + m;
        float bias = b1[j];
        #pragma unroll
        for (int mt = 0; mt < 2; mt++) {
            #pragma unroll
            for (int r = 0; r < 4; r++) {
                int row = mt * 16 + quad * 4 + r;
                h_lds[wave][row][j] = f2b(fmaxf(acc[mt][t][r] + bias, 0.0f));
            }
        }
    }
    __syncthreads();

    // ---- fused layer-2 matmuls: g2 = h@W2l^T, r2 = h@W2r^T (K=128) ----
    floatx4 acc2[2][4], acc3[2][4];
    #pragma unroll
    for (int mt = 0; mt < 2; mt++)
        #pragma unroll
        for (int t = 0; t < 4; t++) { acc2[mt][t] = (floatx4)(0.0f); acc3[mt][t] = (floatx4)(0.0f); }

    #pragma unroll
    for (int ks = 0; ks < 4; ks++) {
        int k0 = ks * 32 + quad * 8;
        short8 hf0 = *(const short8*)&h_lds[wave][m][k0];
        short8 hf1 = *(const short8*)&h_lds[wave][16 + m][k0];
        #pragma unroll
        for (int t = 0; t < 4; t++) {
            short8 bl = *(const short8*)(W2lf + (((ks * 4 + t) * 64 + lane) << 3));
            short8 br = *(const short8*)(W2rf + (((ks * 4 + t) * 64 + lane) << 3));
            acc2[0][t] = __builtin_amdgcn_mfma_f32_16x16x32_bf16(hf0, bl, acc2[0][t], 0, 0, 0);
            acc2[1][t] = __builtin_amdgcn_mfma_f32_16x16x32_bf16(hf1, bl, acc2[1][t], 0, 0, 0);
            acc3[0][t] = __builtin_amdgcn_mfma_f32_16x16x32_bf16(hf0, br, acc3[0][t], 0, 0, 0);
            acc3[1][t] = __builtin_amdgcn_mfma_f32_16x16x32_bf16(hf1, br, acc3[1][t], 0, 0, 0);
        }
    }

    #pragma unroll
    for (int mt = 0; mt < 2; mt++) {
        #pragma unroll
        for (int t = 0; t < 4; t++) {
            #pragma unroll
            for (int r = 0; r < 4; r++) {
                int n = node0 + mt * 16 + quad * 4 + r;
                if (n < N_NODES) {
                    g2b[(size_t)n * 64 + t * 16 + m] = f2b(acc2[mt][t][r]);
                    r2b[(size_t)n * 64 + t * 16 + m] = f2b(acc3[mt][t][r]);
                }
            }
        }
    }
}

// ===========================================================================
// out[n,c] = logsoftmax_c( a2b[n,c] + b2[c] + r2b[n,c] ), 1 node per wave.
__global__ __launch_bounds__(256) void final_kernel(
    const unsigned short* __restrict__ a2b, const unsigned short* __restrict__ r2b,
    const float* __restrict__ b2, float* __restrict__ out)
{
    int node = blockIdx.x * 4 + (threadIdx.x >> 6);
    if (node >= N_NODES) return;
    int c = threadIdx.x & 63;
    float v = b2[c] + b2f(a2b[(size_t)node * 64 + c]) + b2f(r2b[(size_t)node * 64 + c]);
    float mx = v;
    #pragma unroll
    for (int off = 1; off < 64; off <<= 1)
        mx = fmaxf(mx, __shfl_xor(mx, off, 64));
    float e = expf(v - mx);
    float s = e;
    #pragma unroll
    for (int off = 1; off < 64; off <<= 1)
        s += __shfl_xor(s, off, 64);
    out[(size_t)node * 64 + c] = v - mx - logf(s);
}

// ===========================================================================
extern "C" void kernel_launch(void* const* d_in, const int* in_sizes, int n_in,
                              void* d_out, int out_size, void* d_ws, size_t ws_size,
                              hipStream_t stream)
{
    const float* x   = (const float*)d_in[0];
    const int*   ei  = (const int*)d_in[1];
    const float* W1l = (const float*)d_in[2];
    const float* b1  = (const float*)d_in[3];
    const float* W1r = (const float*)d_in[4];
    const float* W2l = (const float*)d_in[5];
    const float* b2  = (const float*)d_in[6];
    const float* W2r = (const float*)d_in[7];
    float* out = (float*)d_out;

    int E = in_sizes[1] / 2;
    const int* src = ei;
    const int* dst = ei + E;

    // Workspace layout (all 16B-aligned sections)
    char* ws = (char*)d_ws;
    int* counts    = (int*)ws;               ws += ((size_t)N_NODES * 4 + 15) / 16 * 16;
    int* row_ptr   = (int*)ws;               ws += ((size_t)(N_NODES + 1) * 4 + 15) / 16 * 16;
    int* cursor    = (int*)ws;               ws += ((size_t)N_NODES * 4 + 15) / 16 * 16;
    int* blockSums = (int*)ws;               ws += ((size_t)128 * 4 + 15) / 16 * 16;
    int* edge_src  = (int*)ws;               ws += ((size_t)E * 4 + 15) / 16 * 16;
    unsigned short* xb   = (unsigned short*)ws;  ws += (size_t)N_NODES * 128 * 2;
    unsigned short* a1b  = (unsigned short*)ws;  ws += (size_t)N_NODES * 128 * 2;
    unsigned short* g2b  = (unsigned short*)ws;  ws += (size_t)N_NODES * 64 * 2;
    unsigned short* r2b  = (unsigned short*)ws;  ws += (size_t)N_NODES * 64 * 2;
    unsigned short* a2b  = (unsigned short*)ws;  ws += (size_t)N_NODES * 64 * 2;
    unsigned short* Wc1f = (unsigned short*)ws;  ws += 128 * 256 * 2;
    unsigned short* W2lf = (unsigned short*)ws;  ws += 64 * 128 * 2;
    unsigned short* W2rf = (unsigned short*)ws;  ws += 64 * 128 * 2;

    // --- prep (bf16 casts + fragment-major weight swizzle) ---
    cvt_x_kernel<<<(N_NODES * 32 + 255) / 256, 256, 0, stream>>>(x, xb);
    prep_w_kernel<<<(49152 + 255) / 256, 256, 0, stream>>>(
        W1l, W1r, W2l, W2r, Wc1f, W2lf, W2rf);

    // --- CSR build ---
    hipMemsetAsync(counts, 0, sizeof(int) * N_NODES, stream);
    hist_kernel<<<(E + 255) / 256, 256, 0, stream>>>(dst, counts, E);
    scanA_kernel<<<SCAN_NBLK, 256, 0, stream>>>(counts, blockSums, N_NODES);
    scanB_kernel<<<1, 128, 0, stream>>>(blockSums, row_ptr, SCAN_NBLK, N_NODES);
    scanC_kernel<<<SCAN_NBLK, 256, 0, stream>>>(counts, blockSums, row_ptr, cursor, N_NODES);
    {
        int fillBlocks = (E + 1024 * FILL_EPT - 1) / (1024 * FILL_EPT);
        fill_kernel<<<fillBlocks, 1024, 0, stream>>>(src, dst, cursor, edge_src, E);
    }

    // --- layer-1 aggregation (D=128, 16 lanes/node) ---
    gather_agg_kernel<16><<<((size_t)N_NODES * 16 + 255) / 256, 256, 0, stream>>>(
        xb, edge_src, row_ptr, a1b);

    // --- fused dense block: layer1 GEMM + relu + both layer2 matmuls ---
    fused_l1_kernel<<<(N_NODES + 127) / 128, 256, 0, stream>>>(
        a1b, xb, Wc1f, b1, W2lf, W2rf, g2b, r2b);

    // --- layer-2 aggregation (D=64, 8 lanes/node) ---
    gather_agg_kernel<8><<<((size_t)N_NODES * 8 + 255) / 256, 256, 0, stream>>>(
        g2b, edge_src, row_ptr, a2b);

    // --- bias + residual + log_softmax ---
    final_kernel<<<(N_NODES + 3) / 4, 256, 0, stream>>>(a2b, r2b, b2, out);
}

// Round 7
// 468.284 us; speedup vs baseline: 12.6934x; 1.0171x over previous
//
#include <hip/hip_runtime.h>
#include <hip/hip_bf16.h>

#define N_NODES 100000
#define SCAN_TILE 1024                       // elements per block in scan
#define SCAN_NBLK ((N_NODES + SCAN_TILE - 1) / SCAN_TILE)   // 98

#define NBUCKET 8
#define BUCKET_W (N_NODES / NBUCKET)         // 12500 (exact)
#define FILL_EPT 7                           // edges per thread in bucket pass

typedef __attribute__((ext_vector_type(8))) short short8;     // 8 bf16 (4 VGPRs)
typedef __attribute__((ext_vector_type(8))) unsigned short u16x8;
typedef __attribute__((ext_vector_type(4))) unsigned short u16x4;
typedef __attribute__((ext_vector_type(4))) float floatx4;

__device__ __forceinline__ float b2f(unsigned short u) {
    return __uint_as_float(((unsigned int)u) << 16);
}
__device__ __forceinline__ unsigned short f2b(float f) {   // RNE
    unsigned int u = __float_as_uint(f);
    unsigned int r = u + 0x7FFFu + ((u >> 16) & 1u);
    return (unsigned short)(r >> 16);
}

// ===========================================================================
// Prep: x -> bf16
__global__ __launch_bounds__(256) void cvt_x_kernel(
    const float* __restrict__ x, unsigned short* __restrict__ xb)
{
    int tid = blockIdx.x * 256 + threadIdx.x;       // one float4 per thread
    int total = N_NODES * 32;                        // N*128/4
    if (tid >= total) return;
    float4 v = ((const float4*)x)[tid];
    u16x4 o;
    o.x = f2b(v.x); o.y = f2b(v.y); o.z = f2b(v.z); o.w = f2b(v.w);
    ((u16x4*)xb)[tid] = o;
}

// Prep weights into MFMA fragment-major layout (see round-6 notes).
__global__ __launch_bounds__(256) void prep_w_kernel(
    const float* __restrict__ W1l, const float* __restrict__ W1r,
    const float* __restrict__ W2l, const float* __restrict__ W2r,
    unsigned short* __restrict__ Wc1f, unsigned short* __restrict__ W2lf,
    unsigned short* __restrict__ W2rf)
{
    int tid = blockIdx.x * 256 + threadIdx.x;
    if (tid < 32768) {                 // 8 ks * 8 t * 64 lane * 8 j
        int j = tid & 7, lane = (tid >> 3) & 63, t = (tid >> 9) & 7, ks = tid >> 12;
        int m = lane & 15, quad = lane >> 4;
        int row = t * 16 + m;
        int k = ks * 32 + quad * 8 + j;
        float v = (k < 128) ? W1l[row * 128 + k] : W1r[row * 128 + (k - 128)];
        Wc1f[tid] = f2b(v);
    } else if (tid < 40960) {          // 4 ks * 4 t * 64 lane * 8 j
        int idx = tid - 32768;
        int j = idx & 7, lane = (idx >> 3) & 63, t = (idx >> 9) & 3, ks = idx >> 11;
        int m = lane & 15, quad = lane >> 4;
        int row = t * 16 + m;
        int k = ks * 32 + quad * 8 + j;
        W2lf[idx] = f2b(W2l[row * 128 + k]);
    } else if (tid < 49152) {
        int idx = tid - 40960;
        int j = idx & 7, lane = (idx >> 3) & 63, t = (idx >> 9) & 3, ks = idx >> 11;
        int m = lane & 15, quad = lane >> 4;
        int row = t * 16 + m;
        int k = ks * 32 + quad * 8 + j;
        W2rf[idx] = f2b(W2r[row * 128 + k]);
    }
}

// ===========================================================================
// CSR build
__global__ __launch_bounds__(256) void hist_kernel(
    const int* __restrict__ dst, int* __restrict__ counts, int E)
{
    int i = blockIdx.x * 256 + threadIdx.x;
    if (i < E) atomicAdd(&counts[dst[i]], 1);
}

__global__ __launch_bounds__(256) void scanA_kernel(
    const int* __restrict__ counts, int* __restrict__ blockSums, int n)
{
    int base = blockIdx.x * SCAN_TILE + threadIdx.x * 4;
    int s = 0;
    if (base + 3 < n) {
        int4 v = *(const int4*)(counts + base);
        s = v.x + v.y + v.z + v.w;
    } else {
        for (int i = 0; i < 4; i++) if (base + i < n) s += counts[base + i];
    }
    #pragma unroll
    for (int off = 1; off < 64; off <<= 1) s += __shfl_xor(s, off, 64);
    __shared__ int wsum[4];
    if ((threadIdx.x & 63) == 0) wsum[threadIdx.x >> 6] = s;
    __syncthreads();
    if (threadIdx.x == 0)
        blockSums[blockIdx.x] = wsum[0] + wsum[1] + wsum[2] + wsum[3];
}

__global__ __launch_bounds__(128) void scanB_kernel(
    int* __restrict__ blockSums, int* __restrict__ row_ptr, int numBlocks, int n)
{
    __shared__ int tmp[128];
    int t = threadIdx.x;
    int v = (t < numBlocks) ? blockSums[t] : 0;
    tmp[t] = v;
    __syncthreads();
    for (int off = 1; off < 128; off <<= 1) {
        int u = (t >= off) ? tmp[t - off] : 0;
        __syncthreads();
        tmp[t] += u;
        __syncthreads();
    }
    if (t < numBlocks) blockSums[t] = (t == 0) ? 0 : tmp[t - 1];
    if (t == 0) row_ptr[n] = tmp[numBlocks - 1];
}

// Phase C: writes row_ptr, cursor, and per-bucket cursors for the fill passes.
__global__ __launch_bounds__(256) void scanC_kernel(
    const int* __restrict__ counts, const int* __restrict__ blockSums,
    int* __restrict__ row_ptr, int* __restrict__ cursor,
    int* __restrict__ bucketCursor, int n)
{
    int t = threadIdx.x;
    int base = blockIdx.x * SCAN_TILE + t * 4;
    int v0 = 0, v1 = 0, v2 = 0, v3 = 0;
    if (base + 3 < n) {
        int4 v = *(const int4*)(counts + base);
        v0 = v.x; v1 = v.y; v2 = v.z; v3 = v.w;
    } else {
        if (base + 0 < n) v0 = counts[base + 0];
        if (base + 1 < n) v1 = counts[base + 1];
        if (base + 2 < n) v2 = counts[base + 2];
        if (base + 3 < n) v3 = counts[base + 3];
    }
    int s = v0 + v1 + v2 + v3;
    __shared__ int tmp[256];
    tmp[t] = s;
    __syncthreads();
    for (int off = 1; off < 256; off <<= 1) {
        int u = (t >= off) ? tmp[t - off] : 0;
        __syncthreads();
        tmp[t] += u;
        __syncthreads();
    }
    int run = blockSums[blockIdx.x] + ((t == 0) ? 0 : tmp[t - 1]);
    #pragma unroll
    for (int i = 0; i < 4; i++) {
        int idx = base + i;
        int vv = (i == 0) ? v0 : (i == 1) ? v1 : (i == 2) ? v2 : v3;
        if (idx < n) {
            row_ptr[idx] = run;
            cursor[idx] = run;
            if (idx % BUCKET_W == 0) bucketCursor[idx / BUCKET_W] = run;
            run += vv;
        }
    }
}

// ===========================================================================
// Fill pass 1: bucket edges by dst-range into pairs[], block-exclusive
// contiguous ranges (LDS rank + one global atomic per block per bucket).
// Write amplification ~1x: each block owns its output lines exclusively.
__global__ __launch_bounds__(1024) void bucket_kernel(
    const int* __restrict__ src, const int* __restrict__ dst,
    int* __restrict__ bucketCursor, int2* __restrict__ pairs, int E)
{
    __shared__ int cnt[NBUCKET];
    __shared__ int base[NBUCKET];
    const int EPB = 1024 * FILL_EPT;
    int e0 = blockIdx.x * EPB;
    if (threadIdx.x < NBUCKET) cnt[threadIdx.x] = 0;
    __syncthreads();

    int es[FILL_EPT], ed[FILL_EPT], rk[FILL_EPT], bk[FILL_EPT];
    #pragma unroll
    for (int j = 0; j < FILL_EPT; j++) {
        int i = e0 + j * 1024 + threadIdx.x;
        if (i < E) {
            es[j] = src[i];
            ed[j] = dst[i];
            bk[j] = ed[j] / BUCKET_W;
            rk[j] = atomicAdd(&cnt[bk[j]], 1);
        } else {
            bk[j] = -1;
        }
    }
    __syncthreads();
    if (threadIdx.x < NBUCKET)
        base[threadIdx.x] = atomicAdd(&bucketCursor[threadIdx.x], cnt[threadIdx.x]);
    __syncthreads();

    #pragma unroll
    for (int j = 0; j < FILL_EPT; j++) {
        if (bk[j] >= 0)
            pairs[(size_t)base[bk[j]] + rk[j]] = make_int2(es[j], ed[j]);
    }
}

// Fill pass 2: XCD-pinned placement. Bucket = blockIdx%8 -> all 32 blocks of
// a bucket land on one XCD (round-robin block->XCD heuristic), so the 800 KB
// edge_src window + 50 KB cursor window for that bucket live in ONE L2 ->
// full-line write-backs (fixes the cross-XCD sector bouncing).
__global__ __launch_bounds__(1024) void fill2_kernel(
    const int2* __restrict__ pairs, const int* __restrict__ row_ptr,
    int* __restrict__ cursor, int* __restrict__ edge_src)
{
    int b = blockIdx.x & (NBUCKET - 1);
    int lb = blockIdx.x >> 3;                       // 0..31 within bucket
    int beg = row_ptr[b * BUCKET_W];
    int end = row_ptr[(b + 1) * BUCKET_W];
    for (int i = beg + lb * 1024 + threadIdx.x; i < end; i += 32 * 1024) {
        int2 p = pairs[i];
        int pos = atomicAdd(&cursor[p.y], 1);
        edge_src[pos] = p.x;
    }
}

// ===========================================================================
// bf16 gather mean-aggregation. L lanes/node, 8 bf16 (16B) per lane, D = 8*L.
template<int L>
__global__ __launch_bounds__(256) void gather_agg_kernel(
    const unsigned short* __restrict__ feat, const int* __restrict__ edge_src,
    const int* __restrict__ row_ptr, unsigned short* __restrict__ aggOut)
{
    int tid = blockIdx.x * 256 + threadIdx.x;
    int node = tid / L;
    int q = tid % L;
    if (node >= N_NODES) return;
    int beg = row_ptr[node];
    int end = row_ptr[node + 1];
    const u16x8* f8 = (const u16x8*)feat;
    float acc[8];
    #pragma unroll
    for (int j = 0; j < 8; j++) acc[j] = 0.0f;
    int e = beg;
    for (; e + 2 <= end; e += 2) {
        int s0 = edge_src[e];
        int s1 = edge_src[e + 1];
        u16x8 v0 = f8[(size_t)s0 * L + q];
        u16x8 v1 = f8[(size_t)s1 * L + q];
        #pragma unroll
        for (int j = 0; j < 8; j++) acc[j] += b2f(v0[j]) + b2f(v1[j]);
    }
    if (e < end) {
        u16x8 v0 = f8[(size_t)edge_src[e] * L + q];
        #pragma unroll
        for (int j = 0; j < 8; j++) acc[j] += b2f(v0[j]);
    }
    int deg = end - beg;
    float inv = (deg > 0) ? 1.0f / (float)deg : 0.0f;
    u16x8 o;
    #pragma unroll
    for (int j = 0; j < 8; j++) o[j] = f2b(acc[j] * inv);
    ((u16x8*)aggOut)[(size_t)node * L + q] = o;
}

// ===========================================================================
// Fused dense block (fragment-major weights, 32 nodes/wave).
__global__ __launch_bounds__(256) void fused_l1_kernel(
    const unsigned short* __restrict__ a1b, const unsigned short* __restrict__ xb,
    const unsigned short* __restrict__ Wc1f, const float* __restrict__ b1,
    const unsigned short* __restrict__ W2lf, const unsigned short* __restrict__ W2rf,
    unsigned short* __restrict__ g2b, unsigned short* __restrict__ r2b)
{
    __shared__ unsigned short h_lds[4][32][136];

    int wave = threadIdx.x >> 6;
    int lane = threadIdx.x & 63;
    int m    = lane & 15;
    int quad = lane >> 4;
    int node0 = blockIdx.x * 128 + wave * 32;

    int n0 = min(node0 + m,      N_NODES - 1);
    int n1 = min(node0 + 16 + m, N_NODES - 1);

    floatx4 acc[2][8];
    #pragma unroll
    for (int mt = 0; mt < 2; mt++)
        #pragma unroll
        for (int t = 0; t < 8; t++) acc[mt][t] = (floatx4)(0.0f);

    #pragma unroll
    for (int ks = 0; ks < 8; ks++) {
        int k0 = ks * 32 + quad * 8;
        const unsigned short* s = (ks < 4) ? a1b : xb;
        int koff = (ks < 4) ? k0 : (k0 - 128);
        short8 af0 = *(const short8*)(s + (size_t)n0 * 128 + koff);
        short8 af1 = *(const short8*)(s + (size_t)n1 * 128 + koff);
        #pragma unroll
        for (int t = 0; t < 8; t++) {
            short8 bf = *(const short8*)(Wc1f + (((ks * 8 + t) * 64 + lane) << 3));
            acc[0][t] = __builtin_amdgcn_mfma_f32_16x16x32_bf16(af0, bf, acc[0][t], 0, 0, 0);
            acc[1][t] = __builtin_amdgcn_mfma_f32_16x16x32_bf16(af1, bf, acc[1][t], 0, 0, 0);
        }
    }

    #pragma unroll
    for (int t = 0; t < 8; t++) {
        int j = t * 16 + m;
        float bias = b1[j];
        #pragma unroll
        for (int mt = 0; mt < 2; mt++) {
            #pragma unroll
            for (int r = 0; r < 4; r++) {
                int row = mt * 16 + quad * 4 + r;
                h_lds[wave][row][j] = f2b(fmaxf(acc[mt][t][r] + bias, 0.0f));
            }
        }
    }
    __syncthreads();

    floatx4 acc2[2][4], acc3[2][4];
    #pragma unroll
    for (int mt = 0; mt < 2; mt++)
        #pragma unroll
        for (int t = 0; t < 4; t++) { acc2[mt][t] = (floatx4)(0.0f); acc3[mt][t] = (floatx4)(0.0f); }

    #pragma unroll
    for (int ks = 0; ks < 4; ks++) {
        int k0 = ks * 32 + quad * 8;
        short8 hf0 = *(const short8*)&h_lds[wave][m][k0];
        short8 hf1 = *(const short8*)&h_lds[wave][16 + m][k0];
        #pragma unroll
        for (int t = 0; t < 4; t++) {
            short8 bl = *(const short8*)(W2lf + (((ks * 4 + t) * 64 + lane) << 3));
            short8 br = *(const short8*)(W2rf + (((ks * 4 + t) * 64 + lane) << 3));
            acc2[0][t] = __builtin_amdgcn_mfma_f32_16x16x32_bf16(hf0, bl, acc2[0][t], 0, 0, 0);
            acc2[1][t] = __builtin_amdgcn_mfma_f32_16x16x32_bf16(hf1, bl, acc2[1][t], 0, 0, 0);
            acc3[0][t] = __builtin_amdgcn_mfma_f32_16x16x32_bf16(hf0, br, acc3[0][t], 0, 0, 0);
            acc3[1][t] = __builtin_amdgcn_mfma_f32_16x16x32_bf16(hf1, br, acc3[1][t], 0, 0, 0);
        }
    }

    #pragma unroll
    for (int mt = 0; mt < 2; mt++) {
        #pragma unroll
        for (int t = 0; t < 4; t++) {
            #pragma unroll
            for (int r = 0; r < 4; r++) {
                int n = node0 + mt * 16 + quad * 4 + r;
                if (n < N_NODES) {
                    g2b[(size_t)n * 64 + t * 16 + m] = f2b(acc2[mt][t][r]);
                    r2b[(size_t)n * 64 + t * 16 + m] = f2b(acc3[mt][t][r]);
                }
            }
        }
    }
}

// ===========================================================================
// out[n,c] = logsoftmax_c( a2b[n,c] + b2[c] + r2b[n,c] ), 1 node per wave.
__global__ __launch_bounds__(256) void final_kernel(
    const unsigned short* __restrict__ a2b, const unsigned short* __restrict__ r2b,
    const float* __restrict__ b2, float* __restrict__ out)
{
    int node = blockIdx.x * 4 + (threadIdx.x >> 6);
    if (node >= N_NODES) return;
    int c = threadIdx.x & 63;
    float v = b2[c] + b2f(a2b[(size_t)node * 64 + c]) + b2f(r2b[(size_t)node * 64 + c]);
    float mx = v;
    #pragma unroll
    for (int off = 1; off < 64; off <<= 1)
        mx = fmaxf(mx, __shfl_xor(mx, off, 64));
    float e = expf(v - mx);
    float s = e;
    #pragma unroll
    for (int off = 1; off < 64; off <<= 1)
        s += __shfl_xor(s, off, 64);
    out[(size_t)node * 64 + c] = v - mx - logf(s);
}

// ===========================================================================
extern "C" void kernel_launch(void* const* d_in, const int* in_sizes, int n_in,
                              void* d_out, int out_size, void* d_ws, size_t ws_size,
                              hipStream_t stream)
{
    const float* x   = (const float*)d_in[0];
    const int*   ei  = (const int*)d_in[1];
    const float* W1l = (const float*)d_in[2];
    const float* b1  = (const float*)d_in[3];
    const float* W1r = (const float*)d_in[4];
    const float* W2l = (const float*)d_in[5];
    const float* b2  = (const float*)d_in[6];
    const float* W2r = (const float*)d_in[7];
    float* out = (float*)d_out;

    int E = in_sizes[1] / 2;
    const int* src = ei;
    const int* dst = ei + E;

    // Workspace layout (all 16B-aligned sections)
    char* ws = (char*)d_ws;
    int* counts       = (int*)ws;            ws += ((size_t)N_NODES * 4 + 15) / 16 * 16;
    int* row_ptr      = (int*)ws;            ws += ((size_t)(N_NODES + 1) * 4 + 15) / 16 * 16;
    int* cursor       = (int*)ws;            ws += ((size_t)N_NODES * 4 + 15) / 16 * 16;
    int* blockSums    = (int*)ws;            ws += ((size_t)128 * 4 + 15) / 16 * 16;
    int* bucketCursor = (int*)ws;            ws += ((size_t)16 * 4 + 15) / 16 * 16;
    int* edge_src     = (int*)ws;            ws += ((size_t)E * 4 + 15) / 16 * 16;
    int2* pairs       = (int2*)ws;           ws += ((size_t)E * 8 + 15) / 16 * 16;
    unsigned short* xb   = (unsigned short*)ws;  ws += (size_t)N_NODES * 128 * 2;
    unsigned short* a1b  = (unsigned short*)ws;  ws += (size_t)N_NODES * 128 * 2;
    unsigned short* g2b  = (unsigned short*)ws;  ws += (size_t)N_NODES * 64 * 2;
    unsigned short* r2b  = (unsigned short*)ws;  ws += (size_t)N_NODES * 64 * 2;
    unsigned short* a2b  = (unsigned short*)ws;  ws += (size_t)N_NODES * 64 * 2;
    unsigned short* Wc1f = (unsigned short*)ws;  ws += 128 * 256 * 2;
    unsigned short* W2lf = (unsigned short*)ws;  ws += 64 * 128 * 2;
    unsigned short* W2rf = (unsigned short*)ws;  ws += 64 * 128 * 2;

    // --- prep (bf16 casts + fragment-major weight swizzle) ---
    cvt_x_kernel<<<(N_NODES * 32 + 255) / 256, 256, 0, stream>>>(x, xb);
    prep_w_kernel<<<(49152 + 255) / 256, 256, 0, stream>>>(
        W1l, W1r, W2l, W2r, Wc1f, W2lf, W2rf);

    // --- CSR build ---
    hipMemsetAsync(counts, 0, sizeof(int) * N_NODES, stream);
    hist_kernel<<<(E + 255) / 256, 256, 0, stream>>>(dst, counts, E);
    scanA_kernel<<<SCAN_NBLK, 256, 0, stream>>>(counts, blockSums, N_NODES);
    scanB_kernel<<<1, 128, 0, stream>>>(blockSums, row_ptr, SCAN_NBLK, N_NODES);
    scanC_kernel<<<SCAN_NBLK, 256, 0, stream>>>(counts, blockSums, row_ptr, cursor,
                                                bucketCursor, N_NODES);
    {
        int EPB = 1024 * FILL_EPT;
        bucket_kernel<<<(E + EPB - 1) / EPB, 1024, 0, stream>>>(
            src, dst, bucketCursor, pairs, E);
        fill2_kernel<<<256, 1024, 0, stream>>>(pairs, row_ptr, cursor, edge_src);
    }

    // --- layer-1 aggregation (D=128, 16 lanes/node) ---
    gather_agg_kernel<16><<<((size_t)N_NODES * 16 + 255) / 256, 256, 0, stream>>>(
        xb, edge_src, row_ptr, a1b);

    // --- fused dense block: layer1 GEMM + relu + both layer2 matmuls ---
    fused_l1_kernel<<<(N_NODES + 127) / 128, 256, 0, stream>>>(
        a1b, xb, Wc1f, b1, W2lf, W2rf, g2b, r2b);

    // --- layer-2 aggregation (D=64, 8 lanes/node) ---
    gather_agg_kernel<8><<<((size_t)N_NODES * 8 + 255) / 256, 256, 0, stream>>>(
        g2b, edge_src, row_ptr, a2b);

    // --- bias + residual + log_softmax ---
    final_kernel<<<(N_NODES + 3) / 4, 256, 0, stream>>>(a2b, r2b, b2, out);
}

// Round 8
// 331.148 us; speedup vs baseline: 17.9500x; 1.4141x over previous
//
#include <hip/hip_runtime.h>
#include <hip/hip_bf16.h>

#define N_NODES 100000
#define NBUCKET 250
#define BUCKET_W 400              // nodes per dst-bucket (N_NODES/NBUCKET exact)
#define BK_EPT 14                 // edges per thread in bucket pass

typedef __attribute__((ext_vector_type(8))) short short8;     // 8 bf16 (4 VGPRs)
typedef __attribute__((ext_vector_type(8))) unsigned short u16x8;
typedef __attribute__((ext_vector_type(4))) unsigned short u16x4;
typedef __attribute__((ext_vector_type(4))) float floatx4;

__device__ __forceinline__ float b2f(unsigned short u) {
    return __uint_as_float(((unsigned int)u) << 16);
}
__device__ __forceinline__ unsigned short f2b(float f) {   // RNE
    unsigned int u = __float_as_uint(f);
    unsigned int r = u + 0x7FFFu + ((u >> 16) & 1u);
    return (unsigned short)(r >> 16);
}

// ===========================================================================
// Fused prep: x->bf16 cast  |  fragment-major weight swizzle  |  bucket cursor
// init. Branch on blockIdx range (all independent).
//   blocks [0, 12500):       xb cast (3.2M float4)
//   blocks [12500, 12692):   weight swizzle (49152 elements)
//   block  12692:            bucketCursor[b] = b * pairCap
__global__ __launch_bounds__(256) void prep_kernel(
    const float* __restrict__ x,
    const float* __restrict__ W1l, const float* __restrict__ W1r,
    const float* __restrict__ W2l, const float* __restrict__ W2r,
    unsigned short* __restrict__ xb, unsigned short* __restrict__ Wc1f,
    unsigned short* __restrict__ W2lf, unsigned short* __restrict__ W2rf,
    int* __restrict__ bucketCursor, int pairCap)
{
    int blk = blockIdx.x;
    if (blk < 12500) {
        int tid = blk * 256 + threadIdx.x;          // one float4 per thread
        float4 v = ((const float4*)x)[tid];
        u16x4 o;
        o.x = f2b(v.x); o.y = f2b(v.y); o.z = f2b(v.z); o.w = f2b(v.w);
        ((u16x4*)xb)[tid] = o;
    } else if (blk < 12692) {
        int tid = (blk - 12500) * 256 + threadIdx.x;
        if (tid < 32768) {                 // 8 ks * 8 t * 64 lane * 8 j
            int j = tid & 7, lane = (tid >> 3) & 63, t = (tid >> 9) & 7, ks = tid >> 12;
            int m = lane & 15, quad = lane >> 4;
            int row = t * 16 + m;
            int k = ks * 32 + quad * 8 + j;
            float v = (k < 128) ? W1l[row * 128 + k] : W1r[row * 128 + (k - 128)];
            Wc1f[tid] = f2b(v);
        } else if (tid < 40960) {          // 4 ks * 4 t * 64 lane * 8 j
            int idx = tid - 32768;
            int j = idx & 7, lane = (idx >> 3) & 63, t = (idx >> 9) & 3, ks = idx >> 11;
            int m = lane & 15, quad = lane >> 4;
            int row = t * 16 + m;
            int k = ks * 32 + quad * 8 + j;
            W2lf[idx] = f2b(W2l[row * 128 + k]);
        } else if (tid < 49152) {
            int idx = tid - 40960;
            int j = idx & 7, lane = (idx >> 3) & 63, t = (idx >> 9) & 3, ks = idx >> 11;
            int m = lane & 15, quad = lane >> 4;
            int row = t * 16 + m;
            int k = ks * 32 + quad * 8 + j;
            W2rf[idx] = f2b(W2r[row * 128 + k]);
        }
    } else {
        if (threadIdx.x < NBUCKET)
            bucketCursor[threadIdx.x] = threadIdx.x * pairCap;
    }
}

// ===========================================================================
// Pass 1: bucket edges into fixed-capacity per-bucket regions of pairs[].
// Block-local LDS rank + one global atomic per (block,bucket) -> each block
// writes exclusive contiguous chunks (clean full-line write-backs).
__global__ __launch_bounds__(1024) void bucket_kernel(
    const int* __restrict__ src, const int* __restrict__ dst,
    int* __restrict__ bucketCursor, int2* __restrict__ pairs, int E)
{
    __shared__ int cnt[NBUCKET];
    __shared__ int base[NBUCKET];
    const int EPB = 1024 * BK_EPT;
    int e0 = blockIdx.x * EPB;
    for (int t = threadIdx.x; t < NBUCKET; t += 1024) cnt[t] = 0;
    __syncthreads();

    int es[BK_EPT], ed[BK_EPT], rk[BK_EPT], bk[BK_EPT];
    #pragma unroll
    for (int j = 0; j < BK_EPT; j++) {
        int i = e0 + j * 1024 + threadIdx.x;
        if (i < E) {
            es[j] = src[i];
            ed[j] = dst[i];
            bk[j] = ed[j] / BUCKET_W;
            rk[j] = atomicAdd(&cnt[bk[j]], 1);
        } else {
            bk[j] = -1;
        }
    }
    __syncthreads();
    for (int t = threadIdx.x; t < NBUCKET; t += 1024)
        base[t] = atomicAdd(&bucketCursor[t], cnt[t]);
    __syncthreads();

    #pragma unroll
    for (int j = 0; j < BK_EPT; j++) {
        if (bk[j] >= 0)
            pairs[(size_t)base[bk[j]] + rk[j]] = make_int2(es[j], ed[j]);
    }
}

// ===========================================================================
// Pass 2: one block per bucket. LDS hist over the bucket's 400 nodes, LDS
// exclusive scan, LDS cursors -> place src ids into edge_src (bucket-local
// contiguous window, block-exclusive => no cross-XCD partial lines), and emit
// per-node (beg, deg) into nodeInfo. Replaces global hist + 3 scan kernels.
__global__ __launch_bounds__(1024) void fill_kernel(
    const int2* __restrict__ pairs, const int* __restrict__ bucketCursor,
    int* __restrict__ edge_src, int2* __restrict__ nodeInfo, int pairCap)
{
    __shared__ int hist[BUCKET_W];
    __shared__ int off[BUCKET_W];
    __shared__ int cur[BUCKET_W];
    int b = blockIdx.x;
    int t = threadIdx.x;
    int base = b * pairCap;
    int cnt = bucketCursor[b] - base;
    int node0 = b * BUCKET_W;

    if (t < BUCKET_W) hist[t] = 0;
    __syncthreads();
    for (int i = t; i < cnt; i += 1024)
        atomicAdd(&hist[pairs[base + i].y - node0], 1);
    __syncthreads();

    if (t < BUCKET_W) off[t] = hist[t];
    __syncthreads();
    for (int o = 1; o < BUCKET_W; o <<= 1) {
        int v = 0;
        if (t < BUCKET_W && t >= o) v = off[t - o];
        __syncthreads();
        if (t < BUCKET_W && t >= o) off[t] += v;
        __syncthreads();
    }
    if (t < BUCKET_W) {
        int gb = base + off[t] - hist[t];     // exclusive prefix
        cur[t] = gb;
        nodeInfo[node0 + t] = make_int2(gb, hist[t]);
    }
    __syncthreads();

    for (int i = t; i < cnt; i += 1024) {
        int2 p = pairs[base + i];
        int pos = atomicAdd(&cur[p.y - node0], 1);
        edge_src[pos] = p.x;
    }
}

// ===========================================================================
// bf16 gather mean-aggregation, unroll-4 (4 outstanding 16B loads/lane).
// L lanes/node, 8 bf16 per lane, D = 8*L. Output pre-divided by max(deg,1).
template<int L>
__global__ __launch_bounds__(256) void gather_agg_kernel(
    const unsigned short* __restrict__ feat, const int* __restrict__ edge_src,
    const int2* __restrict__ nodeInfo, unsigned short* __restrict__ aggOut)
{
    int tid = blockIdx.x * 256 + threadIdx.x;
    int node = tid / L;
    int q = tid % L;
    int2 info = nodeInfo[node];
    int e = info.x, deg = info.y, end = info.x + deg;
    const u16x8* f8 = (const u16x8*)feat;
    float acc[8];
    #pragma unroll
    for (int j = 0; j < 8; j++) acc[j] = 0.0f;
    for (; e + 4 <= end; e += 4) {
        int s0 = edge_src[e + 0];
        int s1 = edge_src[e + 1];
        int s2 = edge_src[e + 2];
        int s3 = edge_src[e + 3];
        u16x8 v0 = f8[(size_t)s0 * L + q];
        u16x8 v1 = f8[(size_t)s1 * L + q];
        u16x8 v2 = f8[(size_t)s2 * L + q];
        u16x8 v3 = f8[(size_t)s3 * L + q];
        #pragma unroll
        for (int j = 0; j < 8; j++)
            acc[j] += (b2f(v0[j]) + b2f(v1[j])) + (b2f(v2[j]) + b2f(v3[j]));
    }
    for (; e < end; e++) {
        u16x8 v0 = f8[(size_t)edge_src[e] * L + q];
        #pragma unroll
        for (int j = 0; j < 8; j++) acc[j] += b2f(v0[j]);
    }
    float inv = (deg > 0) ? 1.0f / (float)deg : 0.0f;
    u16x8 o;
    #pragma unroll
    for (int j = 0; j < 8; j++) o[j] = f2b(acc[j] * inv);
    ((u16x8*)aggOut)[(size_t)node * L + q] = o;
}

// ===========================================================================
// Fused dense block (fragment-major weights, 32 nodes/wave).
__global__ __launch_bounds__(256) void fused_l1_kernel(
    const unsigned short* __restrict__ a1b, const unsigned short* __restrict__ xb,
    const unsigned short* __restrict__ Wc1f, const float* __restrict__ b1,
    const unsigned short* __restrict__ W2lf, const unsigned short* __restrict__ W2rf,
    unsigned short* __restrict__ g2b, unsigned short* __restrict__ r2b)
{
    __shared__ unsigned short h_lds[4][32][136];

    int wave = threadIdx.x >> 6;
    int lane = threadIdx.x & 63;
    int m    = lane & 15;
    int quad = lane >> 4;
    int node0 = blockIdx.x * 128 + wave * 32;

    int n0 = min(node0 + m,      N_NODES - 1);
    int n1 = min(node0 + 16 + m, N_NODES - 1);

    floatx4 acc[2][8];
    #pragma unroll
    for (int mt = 0; mt < 2; mt++)
        #pragma unroll
        for (int t = 0; t < 8; t++) acc[mt][t] = (floatx4)(0.0f);

    #pragma unroll
    for (int ks = 0; ks < 8; ks++) {
        int k0 = ks * 32 + quad * 8;
        const unsigned short* s = (ks < 4) ? a1b : xb;
        int koff = (ks < 4) ? k0 : (k0 - 128);
        short8 af0 = *(const short8*)(s + (size_t)n0 * 128 + koff);
        short8 af1 = *(const short8*)(s + (size_t)n1 * 128 + koff);
        #pragma unroll
        for (int t = 0; t < 8; t++) {
            short8 bf = *(const short8*)(Wc1f + (((ks * 8 + t) * 64 + lane) << 3));
            acc[0][t] = __builtin_amdgcn_mfma_f32_16x16x32_bf16(af0, bf, acc[0][t], 0, 0, 0);
            acc[1][t] = __builtin_amdgcn_mfma_f32_16x16x32_bf16(af1, bf, acc[1][t], 0, 0, 0);
        }
    }

    #pragma unroll
    for (int t = 0; t < 8; t++) {
        int j = t * 16 + m;
        float bias = b1[j];
        #pragma unroll
        for (int mt = 0; mt < 2; mt++) {
            #pragma unroll
            for (int r = 0; r < 4; r++) {
                int row = mt * 16 + quad * 4 + r;
                h_lds[wave][row][j] = f2b(fmaxf(acc[mt][t][r] + bias, 0.0f));
            }
        }
    }
    __syncthreads();

    floatx4 acc2[2][4], acc3[2][4];
    #pragma unroll
    for (int mt = 0; mt < 2; mt++)
        #pragma unroll
        for (int t = 0; t < 4; t++) { acc2[mt][t] = (floatx4)(0.0f); acc3[mt][t] = (floatx4)(0.0f); }

    #pragma unroll
    for (int ks = 0; ks < 4; ks++) {
        int k0 = ks * 32 + quad * 8;
        short8 hf0 = *(const short8*)&h_lds[wave][m][k0];
        short8 hf1 = *(const short8*)&h_lds[wave][16 + m][k0];
        #pragma unroll
        for (int t = 0; t < 4; t++) {
            short8 bl = *(const short8*)(W2lf + (((ks * 4 + t) * 64 + lane) << 3));
            short8 br = *(const short8*)(W2rf + (((ks * 4 + t) * 64 + lane) << 3));
            acc2[0][t] = __builtin_amdgcn_mfma_f32_16x16x32_bf16(hf0, bl, acc2[0][t], 0, 0, 0);
            acc2[1][t] = __builtin_amdgcn_mfma_f32_16x16x32_bf16(hf1, bl, acc2[1][t], 0, 0, 0);
            acc3[0][t] = __builtin_amdgcn_mfma_f32_16x16x32_bf16(hf0, br, acc3[0][t], 0, 0, 0);
            acc3[1][t] = __builtin_amdgcn_mfma_f32_16x16x32_bf16(hf1, br, acc3[1][t], 0, 0, 0);
        }
    }

    #pragma unroll
    for (int mt = 0; mt < 2; mt++) {
        #pragma unroll
        for (int t = 0; t < 4; t++) {
            #pragma unroll
            for (int r = 0; r < 4; r++) {
                int n = node0 + mt * 16 + quad * 4 + r;
                if (n < N_NODES) {
                    g2b[(size_t)n * 64 + t * 16 + m] = f2b(acc2[mt][t][r]);
                    r2b[(size_t)n * 64 + t * 16 + m] = f2b(acc3[mt][t][r]);
                }
            }
        }
    }
}

// ===========================================================================
// Layer-2 gather (L=8) fused with bias + residual + log_softmax.
// 8 lanes per node; lane q owns classes [q*8, q*8+8). Group reductions via
// shfl_xor 1,2,4 (8-lane groups are xor-aligned within the wave).
__global__ __launch_bounds__(256) void gather_final_kernel(
    const unsigned short* __restrict__ g2b, const int* __restrict__ edge_src,
    const int2* __restrict__ nodeInfo, const unsigned short* __restrict__ r2b,
    const float* __restrict__ b2, float* __restrict__ out)
{
    int tid = blockIdx.x * 256 + threadIdx.x;
    int node = tid >> 3;
    int q = tid & 7;
    int2 info = nodeInfo[node];
    int e = info.x, deg = info.y, end = info.x + deg;
    const u16x8* f8 = (const u16x8*)g2b;
    float acc[8];
    #pragma unroll
    for (int j = 0; j < 8; j++) acc[j] = 0.0f;
    for (; e + 4 <= end; e += 4) {
        int s0 = edge_src[e + 0];
        int s1 = edge_src[e + 1];
        int s2 = edge_src[e + 2];
        int s3 = edge_src[e + 3];
        u16x8 v0 = f8[(size_t)s0 * 8 + q];
        u16x8 v1 = f8[(size_t)s1 * 8 + q];
        u16x8 v2 = f8[(size_t)s2 * 8 + q];
        u16x8 v3 = f8[(size_t)s3 * 8 + q];
        #pragma unroll
        for (int j = 0; j < 8; j++)
            acc[j] += (b2f(v0[j]) + b2f(v1[j])) + (b2f(v2[j]) + b2f(v3[j]));
    }
    for (; e < end; e++) {
        u16x8 v0 = f8[(size_t)edge_src[e] * 8 + q];
        #pragma unroll
        for (int j = 0; j < 8; j++) acc[j] += b2f(v0[j]);
    }
    float inv = (deg > 0) ? 1.0f / (float)deg : 0.0f;

    u16x8 rv = ((const u16x8*)r2b)[tid];            // node*8 + q
    float4 blo = ((const float4*)b2)[q * 2];
    float4 bhi = ((const float4*)b2)[q * 2 + 1];
    float v[8];
    v[0] = acc[0] * inv + blo.x + b2f(rv[0]);
    v[1] = acc[1] * inv + blo.y + b2f(rv[1]);
    v[2] = acc[2] * inv + blo.z + b2f(rv[2]);
    v[3] = acc[3] * inv + blo.w + b2f(rv[3]);
    v[4] = acc[4] * inv + bhi.x + b2f(rv[4]);
    v[5] = acc[5] * inv + bhi.y + b2f(rv[5]);
    v[6] = acc[6] * inv + bhi.z + b2f(rv[6]);
    v[7] = acc[7] * inv + bhi.w + b2f(rv[7]);

    float mx = v[0];
    #pragma unroll
    for (int j = 1; j < 8; j++) mx = fmaxf(mx, v[j]);
    mx = fmaxf(mx, __shfl_xor(mx, 1, 64));
    mx = fmaxf(mx, __shfl_xor(mx, 2, 64));
    mx = fmaxf(mx, __shfl_xor(mx, 4, 64));
    float s = 0.0f;
    #pragma unroll
    for (int j = 0; j < 8; j++) s += expf(v[j] - mx);
    s += __shfl_xor(s, 1, 64);
    s += __shfl_xor(s, 2, 64);
    s += __shfl_xor(s, 4, 64);
    float lg = mx + logf(s);

    float4 o0 = make_float4(v[0] - lg, v[1] - lg, v[2] - lg, v[3] - lg);
    float4 o1 = make_float4(v[4] - lg, v[5] - lg, v[6] - lg, v[7] - lg);
    float4* op = (float4*)(out + (size_t)node * 64 + q * 8);
    op[0] = o0;
    op[1] = o1;
}

// ===========================================================================
extern "C" void kernel_launch(void* const* d_in, const int* in_sizes, int n_in,
                              void* d_out, int out_size, void* d_ws, size_t ws_size,
                              hipStream_t stream)
{
    const float* x   = (const float*)d_in[0];
    const int*   ei  = (const int*)d_in[1];
    const float* W1l = (const float*)d_in[2];
    const float* b1  = (const float*)d_in[3];
    const float* W1r = (const float*)d_in[4];
    const float* W2l = (const float*)d_in[5];
    const float* b2  = (const float*)d_in[6];
    const float* W2r = (const float*)d_in[7];
    float* out = (float*)d_out;

    int E = in_sizes[1] / 2;
    const int* src = ei;
    const int* dst = ei + E;

    // Per-bucket pair capacity: 1.5x mean (mean 6400, sigma 80 -> +40 sigma).
    int pairCap = ((E / NBUCKET) * 3 / 2 + 255) / 256 * 256;   // 9600 for E=1.6M

    // Workspace layout (16B-aligned sections)
    char* ws = (char*)d_ws;
    int*  bucketCursor = (int*)ws;   ws += ((size_t)NBUCKET * 4 + 15) / 16 * 16;
    int2* pairs        = (int2*)ws;  ws += (size_t)NBUCKET * pairCap * 8;
    int*  edge_src     = (int*)ws;   ws += (size_t)NBUCKET * pairCap * 4;
    int2* nodeInfo     = (int2*)ws;  ws += (size_t)N_NODES * 8;
    unsigned short* xb   = (unsigned short*)ws;  ws += (size_t)N_NODES * 128 * 2;
    unsigned short* a1b  = (unsigned short*)ws;  ws += (size_t)N_NODES * 128 * 2;
    unsigned short* g2b  = (unsigned short*)ws;  ws += (size_t)N_NODES * 64 * 2;
    unsigned short* r2b  = (unsigned short*)ws;  ws += (size_t)N_NODES * 64 * 2;
    unsigned short* Wc1f = (unsigned short*)ws;  ws += 128 * 256 * 2;
    unsigned short* W2lf = (unsigned short*)ws;  ws += 64 * 128 * 2;
    unsigned short* W2rf = (unsigned short*)ws;  ws += 64 * 128 * 2;

    // 1. prep: bf16 casts + weight swizzle + bucket cursor init
    prep_kernel<<<12693, 256, 0, stream>>>(
        x, W1l, W1r, W2l, W2r, xb, Wc1f, W2lf, W2rf, bucketCursor, pairCap);

    // 2. bucket edges by dst range (block-exclusive chunk writes)
    {
        const int EPB = 1024 * BK_EPT;
        bucket_kernel<<<(E + EPB - 1) / EPB, 1024, 0, stream>>>(
            src, dst, bucketCursor, pairs, E);
    }

    // 3. per-bucket LDS hist/scan/place -> edge_src + nodeInfo (beg,deg)
    fill_kernel<<<NBUCKET, 1024, 0, stream>>>(
        pairs, bucketCursor, edge_src, nodeInfo, pairCap);

    // 4. layer-1 aggregation (D=128, 16 lanes/node)
    gather_agg_kernel<16><<<(N_NODES * 16) / 256, 256, 0, stream>>>(
        xb, edge_src, nodeInfo, a1b);

    // 5. fused dense block: layer1 GEMM + relu + both layer2 matmuls
    fused_l1_kernel<<<(N_NODES + 127) / 128, 256, 0, stream>>>(
        a1b, xb, Wc1f, b1, W2lf, W2rf, g2b, r2b);

    // 6. layer-2 aggregation fused with bias + residual + log_softmax
    gather_final_kernel<<<(N_NODES * 8) / 256, 256, 0, stream>>>(
        g2b, edge_src, nodeInfo, r2b, b2, out);
}